// Round 9
// baseline (476.766 us; speedup 1.0000x reference)
//
#include <hip/hip_runtime.h>
#include <cstdint>

typedef __attribute__((ext_vector_type(8))) short bf16x8;
typedef __attribute__((ext_vector_type(4))) float f32x4;
typedef __attribute__((ext_vector_type(2))) unsigned int u32x2;

#define B_   16
#define C_   512
#define HW_  4096
#define M3_  384
#define HWP_ 1024
#define CV_  256

__device__ __forceinline__ unsigned short f2b(float f) {
  union { float f; unsigned u; } v; v.f = f;
  unsigned r = v.u + 0x7fffu + ((v.u >> 16) & 1u);   // RNE
  return (unsigned short)(r >> 16);
}
__device__ __forceinline__ float b2f(unsigned short b) {
  union { unsigned u; float f; } v; v.u = ((unsigned)b) << 16;
  return v.f;
}
__device__ __forceinline__ f32x4 mfma16(bf16x8 a, bf16x8 b, f32x4 c) {
  return __builtin_amdgcn_mfma_f32_16x16x32_bf16(a, b, c, 0, 0, 0);
}

// ---------------------------------------------------------------- K0: x [b][c][n] f32 -> xb [b][n][c] bf16
__global__ __launch_bounds__(256) void k_transpose(const float* __restrict__ x,
                                                   unsigned short* __restrict__ xb) {
  __shared__ unsigned short t[64][66];
  const int b = blockIdx.z, k0 = blockIdx.y * 64, n0 = blockIdx.x * 64;
  const float* xp = x + (size_t)b * C_ * HW_;
  const int ln = threadIdx.x & 63, g = threadIdx.x >> 6;
  for (int kk = g; kk < 64; kk += 4)
    t[kk][ln] = f2b(xp[(size_t)(k0 + kk) * HW_ + n0 + ln]);
  __syncthreads();
  unsigned short* xo = xb + (size_t)b * HW_ * C_;
  for (int nn = g; nn < 64; nn += 4)
    xo[(size_t)(n0 + nn) * C_ + k0 + ln] = t[ln][nn];
}

// ---------------------------------------------------------------- K0b: transpose the 4 weight matrices (f32)
__global__ __launch_bounds__(256) void k_wtrans(
    const float* __restrict__ Wq, const float* __restrict__ Wk,
    const float* __restrict__ Wv, const float* __restrict__ Wo,
    float* __restrict__ wt) {
  const float* w; int out, in; float* dst;
  switch (blockIdx.z) {
    case 0: w = Wq; out = 64;  in = 512; dst = wt;          break;
    case 1: w = Wk; out = 64;  in = 512; dst = wt + 32768;  break;
    case 2: w = Wv; out = 256; in = 512; dst = wt + 65536;  break;
    default: w = Wo; out = 512; in = 256; dst = wt + 196608; break;
  }
  const int o0 = blockIdx.y * 64, i0 = blockIdx.x * 64;
  if (o0 >= out || i0 >= in) return;
  __shared__ float t[64][65];
  const int ln = threadIdx.x & 63, g = threadIdx.x >> 6;
  for (int oo = g; oo < 64; oo += 4)
    t[oo][ln] = w[(size_t)(o0 + oo) * in + i0 + ln];
  __syncthreads();
  for (int ii = g; ii < 64; ii += 4)
    dst[(size_t)(i0 + ii) * out + o0 + ln] = t[ln][ii];
}

// ---------------------------------------------------------------- K1: spectral norm, 1024 thr / matrix
__device__ __forceinline__ float breduce1024(float val, float* red) {
  __syncthreads();
#pragma unroll
  for (int off = 32; off > 0; off >>= 1) val += __shfl_down(val, off);
  if ((threadIdx.x & 63) == 0) red[threadIdx.x >> 6] = val;
  __syncthreads();
  float s = 0.f;
#pragma unroll
  for (int i = 0; i < 16; ++i) s += red[i];
  return s;
}

__global__ __launch_bounds__(1024) void k_specnorm(
    const float* __restrict__ Wq, const float* __restrict__ Wk,
    const float* __restrict__ Wv, const float* __restrict__ Wo,
    const float* __restrict__ wt,
    unsigned short* __restrict__ wqkv, unsigned short* __restrict__ wob) {
  __shared__ float u[512], v[512];
  __shared__ float part[4096];
  __shared__ float red[16];
  const float* w; const float* wT; int out, in; unsigned short* dst;
  switch (blockIdx.x) {
    case 0: w = Wq; wT = wt;          out = 64;  in = 512; dst = wqkv;             break;
    case 1: w = Wk; wT = wt + 32768;  out = 64;  in = 512; dst = wqkv + 64 * 512;  break;
    case 2: w = Wv; wT = wt + 65536;  out = 256; in = 512; dst = wqkv + 128 * 512; break;
    default: w = Wo; wT = wt + 196608; out = 512; in = 256; dst = wob;             break;
  }
  const int tid = threadIdx.x;
  const float rs = rsqrtf((float)out);
  if (tid < out) u[tid] = rs;
  __syncthreads();
  for (int it = 0; it < 5; ++it) {
    {
      const int G = in >> 2, nch = 1024 / G;
      const int ch = tid / G, grp = tid - ch * G;
      const int rpc = out / nch, obase = ch * rpc;
      f32x4 acc = {0.f, 0.f, 0.f, 0.f};
#pragma unroll 8
      for (int r = 0; r < rpc; ++r) {
        const int o = obase + r;
        const f32x4 wv = *reinterpret_cast<const f32x4*>(&w[(size_t)o * in + grp * 4]);
        const float uo = u[o];
        acc[0] += wv[0] * uo; acc[1] += wv[1] * uo;
        acc[2] += wv[2] * uo; acc[3] += wv[3] * uo;
      }
      *reinterpret_cast<f32x4*>(&part[ch * in + grp * 4]) = acc;
      __syncthreads();
      if (tid < in) {
        float s = 0.f;
        for (int c2 = 0; c2 < nch; ++c2) s += part[c2 * in + tid];
        v[tid] = s;
      }
    }
    {
      float ss = 0.f;
      __syncthreads();
      if (tid < in) ss = v[tid] * v[tid];
      ss = breduce1024(ss, red);
      const float sv = 1.f / (sqrtf(ss) + 1e-12f);
      if (tid < in) v[tid] *= sv;
      __syncthreads();
    }
    {
      const int G = out >> 2, nch = 1024 / G;
      const int ch = tid / G, grp = tid - ch * G;
      const int cpc = in / nch, cbase = ch * cpc;
      f32x4 acc = {0.f, 0.f, 0.f, 0.f};
#pragma unroll 8
      for (int r = 0; r < cpc; ++r) {
        const int c = cbase + r;
        const f32x4 wv = *reinterpret_cast<const f32x4*>(&wT[(size_t)c * out + grp * 4]);
        const float vc = v[c];
        acc[0] += wv[0] * vc; acc[1] += wv[1] * vc;
        acc[2] += wv[2] * vc; acc[3] += wv[3] * vc;
      }
      *reinterpret_cast<f32x4*>(&part[ch * out + grp * 4]) = acc;
      __syncthreads();
      if (tid < out) {
        float s = 0.f;
        for (int c2 = 0; c2 < nch; ++c2) s += part[c2 * out + tid];
        u[tid] = s;
      }
    }
    {
      float su = 0.f;
      __syncthreads();
      if (tid < out) su = u[tid] * u[tid];
      su = breduce1024(su, red);
      const float sv2 = 1.f / (sqrtf(su) + 1e-12f);
      if (tid < out) u[tid] *= sv2;
      __syncthreads();
    }
  }
  float sp = 0.f;
  {
    const int G = out >> 2, nch = 1024 / G;
    const int ch = tid / G, grp = tid - ch * G;
    const int cpc = in / nch, cbase = ch * cpc;
    f32x4 acc = {0.f, 0.f, 0.f, 0.f};
#pragma unroll 8
    for (int r = 0; r < cpc; ++r) {
      const int c = cbase + r;
      const f32x4 wv = *reinterpret_cast<const f32x4*>(&wT[(size_t)c * out + grp * 4]);
      const float vc = v[c];
      acc[0] += wv[0] * vc; acc[1] += wv[1] * vc;
      acc[2] += wv[2] * vc; acc[3] += wv[3] * vc;
    }
    *reinterpret_cast<f32x4*>(&part[ch * out + grp * 4]) = acc;
    __syncthreads();
    if (tid < out) {
      float s = 0.f;
      for (int c2 = 0; c2 < nch; ++c2) s += part[c2 * out + tid];
      sp = s * u[tid];
    }
  }
  sp = breduce1024(sp, red);
  const float oscale = (blockIdx.x == 0) ? 1.44269504f : 1.0f;
  const float inv_sigma = (1.f / sp) * oscale;
  const int total = out * in;
  for (int i = tid * 4; i < total; i += 4096) {
    const f32x4 wv = *reinterpret_cast<const f32x4*>(&w[i]);
    u32x2 pw;
    pw[0] = ((unsigned)f2b(wv[1] * inv_sigma) << 16) | f2b(wv[0] * inv_sigma);
    pw[1] = ((unsigned)f2b(wv[3] * inv_sigma) << 16) | f2b(wv[2] * inv_sigma);
    *reinterpret_cast<u32x2*>(&dst[i]) = pw;
  }
}

// ---------------------------------------------------------------- K2: Yt[b][n][m] = xb[b][n][k] * wqkv[m][k]
__global__ __launch_bounds__(256) void k_gemm_qkv(
    const unsigned short* __restrict__ xb, const unsigned short* __restrict__ wqkv,
    unsigned short* __restrict__ yt) {
  __shared__ alignas(16) char smem[32768];
  unsigned short* As = (unsigned short*)smem;
  unsigned short* Bs = (unsigned short*)(smem + 16384);
  const int lid = blockIdx.x;
  const int swz = (lid & 7) * 192 + (lid >> 3);
  const int mt = swz % 3, rest = swz / 3;
  const int nt = rest & 31, b = rest >> 5;
  const int n0 = nt * 128, m0 = mt * 128;
  const unsigned short* Ap = xb + (size_t)b * HW_ * C_ + (size_t)n0 * C_;
  const unsigned short* Bp = wqkv + (size_t)m0 * C_;
  const int tid = threadIdx.x, lane = tid & 63, wid = tid >> 6;
  const int wn = (wid >> 1) * 64, wm = (wid & 1) * 64;
  f32x4 acc[4][4] = {};
  for (int k0 = 0; k0 < C_; k0 += 64) {
    __syncthreads();
#pragma unroll
    for (int i = 0; i < 4; ++i) {
      const int r = i * 32 + (tid >> 3);
      const int s = tid & 7, ss = s ^ (r & 7);
      *reinterpret_cast<f32x4*>(&As[r * 64 + ss * 8]) =
          *reinterpret_cast<const f32x4*>(&Ap[(size_t)r * C_ + k0 + s * 8]);
      *reinterpret_cast<f32x4*>(&Bs[r * 64 + ss * 8]) =
          *reinterpret_cast<const f32x4*>(&Bp[(size_t)r * C_ + k0 + s * 8]);
    }
    __syncthreads();
#pragma unroll
    for (int kk = 0; kk < 2; ++kk) {
      bf16x8 af[4], bfr[4];
#pragma unroll
      for (int i = 0; i < 4; ++i) {
        const int r = wn + i * 16 + (lane & 15);
        const int slot = (kk * 4 + (lane >> 4)) ^ (r & 7);
        af[i] = *reinterpret_cast<const bf16x8*>(&As[r * 64 + slot * 8]);
      }
#pragma unroll
      for (int j = 0; j < 4; ++j) {
        const int r = wm + j * 16 + (lane & 15);
        const int slot = (kk * 4 + (lane >> 4)) ^ (r & 7);
        bfr[j] = *reinterpret_cast<const bf16x8*>(&Bs[r * 64 + slot * 8]);
      }
#pragma unroll
      for (int i = 0; i < 4; ++i)
#pragma unroll
        for (int j = 0; j < 4; ++j) acc[i][j] = mfma16(af[i], bfr[j], acc[i][j]);
    }
  }
  unsigned short* eps = (unsigned short*)smem;
  unsigned short* Y = yt + (size_t)b * HW_ * M3_;
#pragma unroll
  for (int h = 0; h < 2; ++h) {
    __syncthreads();
    if ((wid >> 1) == h) {
#pragma unroll
      for (int i = 0; i < 4; ++i)
#pragma unroll
        for (int j = 0; j < 4; ++j)
#pragma unroll
          for (int r = 0; r < 4; ++r) {
            const int nl = i * 16 + (lane >> 4) * 4 + r;
            const int ml = wm + j * 16 + (lane & 15);
            eps[nl * 136 + ml] = f2b(acc[i][j][r]);
          }
    }
    __syncthreads();
#pragma unroll
    for (int t = 0; t < 4; ++t) {
      const int row = t * 16 + (tid >> 4);
      const int m8 = (tid & 15) * 8;
      *reinterpret_cast<f32x4*>(&Y[(size_t)(n0 + h * 64 + row) * M3_ + m0 + m8]) =
          *reinterpret_cast<const f32x4*>(&eps[row * 136 + m8]);
    }
  }
}

// ---------------------------------------------------------------- K3a: gt[b][mp][c] = maxpool(Yt cols 64..127)
__global__ __launch_bounds__(256) void k_pool_g(const unsigned short* __restrict__ yt,
                                                unsigned short* __restrict__ gt) {
  const int b = blockIdx.y, mp0 = blockIdx.x * 64;
  const int c = threadIdx.x & 63, dm = threadIdx.x >> 6;
  const unsigned short* Y = yt + (size_t)b * HW_ * M3_;
  unsigned short* G = gt + (size_t)b * HWP_ * 64;
  for (int mm = dm; mm < 64; mm += 4) {
    const int mp = mp0 + mm;
    const int n00 = (mp >> 5) * 128 + (mp & 31) * 2;
    const float a0 = b2f(Y[(size_t)n00 * M3_ + 64 + c]);
    const float a1 = b2f(Y[(size_t)(n00 + 1) * M3_ + 64 + c]);
    const float a2 = b2f(Y[(size_t)(n00 + 64) * M3_ + 64 + c]);
    const float a3 = b2f(Y[(size_t)(n00 + 65) * M3_ + 64 + c]);
    G[(size_t)mp * 64 + c] = f2b(fmaxf(fmaxf(a0, a1), fmaxf(a2, a3)));
  }
}

// ---------------------------------------------------------------- K3b: vt[b][cv][mp] = maxpool(Yt cols 128..383)^T
__global__ __launch_bounds__(256) void k_pool_vt(const unsigned short* __restrict__ yt,
                                                 unsigned short* __restrict__ vt) {
  __shared__ unsigned short t[64][66];
  const int b = blockIdx.z, mp0 = blockIdx.x * 64, cv0 = blockIdx.y * 64;
  const unsigned short* Y = yt + (size_t)b * HW_ * M3_;
  const int c = threadIdx.x & 63, dm = threadIdx.x >> 6;
  for (int mm = dm; mm < 64; mm += 4) {
    const int mp = mp0 + mm;
    const int n00 = (mp >> 5) * 128 + (mp & 31) * 2;
    const float a0 = b2f(Y[(size_t)n00 * M3_ + 128 + cv0 + c]);
    const float a1 = b2f(Y[(size_t)(n00 + 1) * M3_ + 128 + cv0 + c]);
    const float a2 = b2f(Y[(size_t)(n00 + 64) * M3_ + 128 + cv0 + c]);
    const float a3 = b2f(Y[(size_t)(n00 + 65) * M3_ + 128 + cv0 + c]);
    t[mm][c] = f2b(fmaxf(fmaxf(a0, a1), fmaxf(a2, a3)));
  }
  __syncthreads();
  unsigned short* V = vt + (size_t)b * CV_ * HWP_;
  for (int cc = dm; cc < 64; cc += 4)
    V[(size_t)(cv0 + cc) * HWP_ + mp0 + c] = t[c][cc];
}

// ---------------------------------------------------------------- K4: flash attention, cv-ownership
// 4 waves / 64 q per block. Each wave: softmax-owns 16 q, PV-owns 64 cv.
// K/V fragments DIRECT from global (V read 1x per block; prefetched 1 tile
// ahead). Only P in LDS (double-buffered -> 1 barrier/tile). Defer-max with
// cross-wave alpha via dbuf'd aLds (rare path).
__global__ __launch_bounds__(256, 3) void k_attn(
    const unsigned short* __restrict__ yt, const unsigned short* __restrict__ gt,
    const unsigned short* __restrict__ vt, unsigned short* __restrict__ oat) {
  __shared__ alignas(16) char smem[34048];
  // loop-time: P dbuf @0,@8192 (8KB each); aLds f32[2][64] @16384; fLds int[2][4] @16896
  // epilogue:  eps bf16[64][264] @0 (33792B); lLds f32[64] @33792
  float* aLds = (float*)(smem + 16384);
  int* fLds = (int*)(smem + 16896);
  const int lid = blockIdx.x;                              // 1024 blocks
  const int swz = (lid & 7) * 128 + (lid >> 3);
  const int q0 = (swz & 63) * 64, b = swz >> 6;
  const int tid = threadIdx.x, lane = tid & 63, wid = tid >> 6;  // 4 waves
  const int q = lane & 15, g = lane >> 4;
  const int cvb = wid * 64;
  const unsigned short* Qg = yt + (size_t)b * HW_ * M3_ + (size_t)q0 * M3_;
  const unsigned short* Gg = gt + (size_t)b * HWP_ * 64;
  const unsigned short* Vg = vt + (size_t)b * CV_ * HWP_ + (size_t)cvb * HWP_;
  // Q fragments (held all kernel)
  bf16x8 qf[2];
#pragma unroll
  for (int kk = 0; kk < 2; ++kk)
    qf[kk] = *reinterpret_cast<const bf16x8*>(&Qg[(size_t)(wid * 16 + q) * M3_ + kk * 32 + g * 8]);
  // prefetch K/V fragments for tile 0 (addressing verified in R5)
  bf16x8 kf[2][4], vf[2][4];
#pragma unroll
  for (int kk = 0; kk < 2; ++kk)
#pragma unroll
    for (int i = 0; i < 4; ++i)
      kf[kk][i] = *reinterpret_cast<const bf16x8*>(&Gg[(size_t)(i * 16 + q) * 64 + kk * 32 + g * 8]);
#pragma unroll
  for (int kk = 0; kk < 2; ++kk)
#pragma unroll
    for (int j = 0; j < 4; ++j)
      vf[kk][j] = *reinterpret_cast<const bf16x8*>(&Vg[(size_t)(j * 16 + q) * HWP_ + kk * 32 + g * 8]);
  f32x4 oacc[4][4] = {};
  float m_run = -1e30f, l_run = 0.f;
  for (int it = 0; it < 16; ++it) {
    const int cur = it & 1;
    unsigned short* P = (unsigned short*)smem + cur * 4096;
    // QK^T (swapped): sacc rows kv, col q (this wave's 16 q)
    f32x4 sacc[4] = {};
#pragma unroll
    for (int kk = 0; kk < 2; ++kk)
#pragma unroll
      for (int i = 0; i < 4; ++i) sacc[i] = mfma16(kf[kk][i], qf[kk], sacc[i]);
    if (it < 15) {  // prefetch next K frags (kf dead now); hides under softmax+barrier+PV
      const int kvn = (it + 1) * 64;
#pragma unroll
      for (int kk = 0; kk < 2; ++kk)
#pragma unroll
        for (int i = 0; i < 4; ++i)
          kf[kk][i] = *reinterpret_cast<const bf16x8*>(&Gg[(size_t)(kvn + i * 16 + q) * 64 + kk * 32 + g * 8]);
    }
    // online softmax (log2 domain), defer-max, per-wave on its 16 q
    float tmax = -1e30f;
#pragma unroll
    for (int i = 0; i < 4; ++i)
#pragma unroll
      for (int r = 0; r < 4; ++r) tmax = fmaxf(tmax, sacc[i][r]);
    tmax = fmaxf(tmax, __shfl_xor(tmax, 16));
    tmax = fmaxf(tmax, __shfl_xor(tmax, 32));
    float alpha = 1.f;
    int resc = 0;
    if (__any(tmax > m_run + 11.0f)) {
      const float mnew = fmaxf(m_run, tmax);
      alpha = exp2f(m_run - mnew);
      m_run = mnew;
      l_run *= alpha;
      resc = 1;
    }
    if (lane < 16) aLds[cur * 64 + wid * 16 + lane] = alpha;
    if (lane == 0) fLds[cur * 4 + wid] = resc;
    const int qg = wid * 16 + q;
    float lsum = 0.f;
#pragma unroll
    for (int i = 0; i < 4; ++i) {
      const float p0 = exp2f(sacc[i][0] - m_run);
      const float p1 = exp2f(sacc[i][1] - m_run);
      const float p2 = exp2f(sacc[i][2] - m_run);
      const float p3 = exp2f(sacc[i][3] - m_run);
      lsum += (p0 + p1) + (p2 + p3);
      u32x2 pw;
      pw[0] = ((unsigned)f2b(p1) << 16) | f2b(p0);
      pw[1] = ((unsigned)f2b(p3) << 16) | f2b(p2);
      const int sl = (2 * i + (g >> 1)) ^ (q & 7);   // (kv>>3) ^ (row&7), row&7 == q&7
      *reinterpret_cast<u32x2*>(&P[qg * 64 + sl * 8 + (g & 1) * 4]) = pw;
    }
    lsum += __shfl_xor(lsum, 16);
    lsum += __shfl_xor(lsum, 32);
    l_run += lsum;
    __syncthreads();
    // rescale oacc (rare after first tiles); alphas for all 64 q from aLds
    if (fLds[cur * 4 + 0] | fLds[cur * 4 + 1] | fLds[cur * 4 + 2] | fLds[cur * 4 + 3]) {
#pragma unroll
      for (int f = 0; f < 4; ++f) {
        float al[4];
#pragma unroll
        for (int r = 0; r < 4; ++r) al[r] = aLds[cur * 64 + f * 16 + g * 4 + r];
#pragma unroll
        for (int j = 0; j < 4; ++j) {
          oacc[f][j][0] *= al[0]; oacc[f][j][1] *= al[1];
          oacc[f][j][2] *= al[2]; oacc[f][j][3] *= al[3];
        }
      }
    }
    // PV: pa from shared P (all 64 q), vf from regs (own 64 cv)
    __builtin_amdgcn_s_setprio(1);
#pragma unroll
    for (int kk = 0; kk < 2; ++kk) {
#pragma unroll
      for (int f = 0; f < 4; ++f) {
        const int row = f * 16 + q;
        const bf16x8 pa = *reinterpret_cast<const bf16x8*>(
            &P[row * 64 + (((kk * 4 + g) ^ (q & 7))) * 8]);
#pragma unroll
        for (int j = 0; j < 4; ++j)
          oacc[f][j] = mfma16(pa, vf[kk][j], oacc[f][j]);
      }
    }
    __builtin_amdgcn_s_setprio(0);
    if (it < 15) {  // prefetch next V frags (vf dead now); hides under next QK^T+softmax
      const int kvn = (it + 1) * 64;
#pragma unroll
      for (int kk = 0; kk < 2; ++kk)
#pragma unroll
        for (int j = 0; j < 4; ++j)
          vf[kk][j] = *reinterpret_cast<const bf16x8*>(&Vg[(size_t)(j * 16 + q) * HWP_ + kvn + kk * 32 + g * 8]);
    }
  }
  // epilogue: linv for all 64 q via lLds (disjoint from eps), repack, store
  float* lLds = (float*)(smem + 33792);
  if (lane < 16) lLds[wid * 16 + lane] = 1.f / l_run;
  __syncthreads();
  float linv[4][4];
#pragma unroll
  for (int f = 0; f < 4; ++f)
#pragma unroll
    for (int r = 0; r < 4; ++r) linv[f][r] = lLds[f * 16 + g * 4 + r];
  unsigned short* eps = (unsigned short*)smem;   // 64 x 264
#pragma unroll
  for (int f = 0; f < 4; ++f)
#pragma unroll
    for (int j = 0; j < 4; ++j)
#pragma unroll
      for (int r = 0; r < 4; ++r) {
        const int row = f * 16 + g * 4 + r;
        const int cv = cvb + j * 16 + q;
        eps[row * 264 + cv] = f2b(oacc[f][j][r] * linv[f][r]);
      }
  __syncthreads();
  unsigned short* O = oat + (size_t)b * HW_ * CV_ + (size_t)q0 * CV_;
#pragma unroll
  for (int t = 0; t < 8; ++t) {
    const int row = t * 8 + (tid >> 5);
    const int cv8 = (tid & 31) * 8;
    *reinterpret_cast<f32x4*>(&O[(size_t)row * CV_ + cv8]) =
        *reinterpret_cast<const f32x4*>(&eps[row * 264 + cv8]);
  }
}

// ---------------------------------------------------------------- K5: out[b][co][n] = gamma * wo@Oatt^T + x
__global__ __launch_bounds__(256) void k_gemm_out(
    const unsigned short* __restrict__ oat, const unsigned short* __restrict__ wob,
    const float* __restrict__ x, const float* __restrict__ gamma,
    float* __restrict__ out) {
  __shared__ alignas(16) char smem[32768];
  unsigned short* As = (unsigned short*)smem;
  unsigned short* Bs = (unsigned short*)(smem + 16384);
  const int lid = blockIdx.x;
  const int swz = (lid & 7) * 256 + (lid >> 3);
  const int ct = swz & 3, nt = (swz >> 2) & 31, b = swz >> 7;
  const int n0 = nt * 128, co0 = ct * 128;
  const unsigned short* Ap = wob + (size_t)co0 * CV_;
  const unsigned short* Bp = oat + (size_t)b * HW_ * CV_ + (size_t)n0 * CV_;
  const int tid = threadIdx.x, lane = tid & 63, wid = tid >> 6;
  const int wc = (wid >> 1) * 64, wn = (wid & 1) * 64;
  f32x4 acc[4][4] = {};
  for (int k0 = 0; k0 < CV_; k0 += 64) {
    __syncthreads();
#pragma unroll
    for (int i = 0; i < 4; ++i) {
      const int r = i * 32 + (tid >> 3);
      const int s = tid & 7, ss = s ^ (r & 7);
      *reinterpret_cast<f32x4*>(&As[r * 64 + ss * 8]) =
          *reinterpret_cast<const f32x4*>(&Ap[(size_t)r * CV_ + k0 + s * 8]);
      *reinterpret_cast<f32x4*>(&Bs[r * 64 + ss * 8]) =
          *reinterpret_cast<const f32x4*>(&Bp[(size_t)r * CV_ + k0 + s * 8]);
    }
    __syncthreads();
#pragma unroll
    for (int kk = 0; kk < 2; ++kk) {
      bf16x8 af[4], bfr[4];
#pragma unroll
      for (int i = 0; i < 4; ++i) {
        const int r = wc + i * 16 + (lane & 15);
        const int slot = (kk * 4 + (lane >> 4)) ^ (r & 7);
        af[i] = *reinterpret_cast<const bf16x8*>(&As[r * 64 + slot * 8]);
      }
#pragma unroll
      for (int j = 0; j < 4; ++j) {
        const int r = wn + j * 16 + (lane & 15);
        const int slot = (kk * 4 + (lane >> 4)) ^ (r & 7);
        bfr[j] = *reinterpret_cast<const bf16x8*>(&Bs[r * 64 + slot * 8]);
      }
#pragma unroll
      for (int i = 0; i < 4; ++i)
#pragma unroll
        for (int j = 0; j < 4; ++j) acc[i][j] = mfma16(af[i], bfr[j], acc[i][j]);
    }
  }
  float* eps = (float*)smem;
  const float g = gamma[0];
  const size_t base = (size_t)b * C_ * HW_;
#pragma unroll
  for (int h = 0; h < 4; ++h) {
    __syncthreads();
    if ((wid >> 1) == (h >> 1)) {
#pragma unroll
      for (int ii = 0; ii < 2; ++ii) {
        const int i = (h & 1) * 2 + ii;
#pragma unroll
        for (int j = 0; j < 4; ++j)
#pragma unroll
          for (int r = 0; r < 4; ++r) {
            const int col2 = ii * 16 + (lane >> 4) * 4 + r;
            const int nl = wn + j * 16 + (lane & 15);
            eps[col2 * 132 + nl] = acc[i][j][r];
          }
      }
    }
    __syncthreads();
#pragma unroll
    for (int t = 0; t < 4; ++t) {
      const int row = t * 8 + (tid >> 5);
      const int col = (tid & 31) * 4;
      const size_t goff = base + (size_t)(co0 + h * 32 + row) * HW_ + n0 + col;
      const f32x4 xv = *reinterpret_cast<const f32x4*>(&x[goff]);
      const f32x4 av = *reinterpret_cast<const f32x4*>(&eps[row * 132 + col]);
      f32x4 ov;
      ov[0] = g * av[0] + xv[0];
      ov[1] = g * av[1] + xv[1];
      ov[2] = g * av[2] + xv[2];
      ov[3] = g * av[3] + xv[3];
      *reinterpret_cast<f32x4*>(&out[goff]) = ov;
    }
  }
}

// ---------------------------------------------------------------- launcher
extern "C" void kernel_launch(void* const* d_in, const int* in_sizes, int n_in,
                              void* d_out, int out_size, void* d_ws, size_t ws_size,
                              hipStream_t stream) {
  (void)in_sizes; (void)n_in; (void)out_size; (void)ws_size;
  const float* x     = (const float*)d_in[0];
  const float* Wq    = (const float*)d_in[1];
  const float* Wk    = (const float*)d_in[2];
  const float* Wv    = (const float*)d_in[3];
  const float* Wo    = (const float*)d_in[4];
  const float* gamma = (const float*)d_in[5];
  float* out = (float*)d_out;
  char* ws = (char*)d_ws;

  unsigned short* wqkv = (unsigned short*)(ws);                 // 384*512*2
  unsigned short* wob  = (unsigned short*)(ws + 393216);        // 512*256*2
  unsigned short* xb   = (unsigned short*)(ws + 655360);        // 64MB
  unsigned short* yt   = (unsigned short*)(ws + 67764224);      // 48MB
  unsigned short* gt   = (unsigned short*)(ws + 118095872);     // 2MB
  unsigned short* vt   = (unsigned short*)(ws + 120193024);     // 8MB
  unsigned short* oat  = xb;   // alias: xb dead after k_gemm_qkv
  float* wt = (float*)yt;      // alias: wT only live during specnorm (yt written later)

  k_transpose<<<dim3(64, 8, 16), 256, 0, stream>>>(x, xb);
  k_wtrans<<<dim3(8, 8, 4), 256, 0, stream>>>(Wq, Wk, Wv, Wo, wt);
  k_specnorm<<<4, 1024, 0, stream>>>(Wq, Wk, Wv, Wo, wt, wqkv, wob);
  k_gemm_qkv<<<1536, 256, 0, stream>>>(xb, wqkv, yt);
  k_pool_g<<<dim3(16, 16), 256, 0, stream>>>(yt, gt);
  k_pool_vt<<<dim3(16, 4, 16), 256, 0, stream>>>(yt, vt);
  k_attn<<<1024, 256, 0, stream>>>(yt, gt, vt, oat);
  k_gemm_out<<<2048, 256, 0, stream>>>(oat, wob, x, gamma, out);
}

// Round 10
// 323.778 us; speedup vs baseline: 1.4725x; 1.4725x over previous
//
#include <hip/hip_runtime.h>
#include <cstdint>

typedef __attribute__((ext_vector_type(8))) short bf16x8;
typedef __attribute__((ext_vector_type(4))) float f32x4;
typedef __attribute__((ext_vector_type(2))) unsigned int u32x2;

#define B_   16
#define C_   512
#define HW_  4096
#define M3_  384
#define HWP_ 1024
#define CV_  256

__device__ __forceinline__ unsigned short f2b(float f) {
  union { float f; unsigned u; } v; v.f = f;
  unsigned r = v.u + 0x7fffu + ((v.u >> 16) & 1u);   // RNE
  return (unsigned short)(r >> 16);
}
__device__ __forceinline__ float b2f(unsigned short b) {
  union { unsigned u; float f; } v; v.u = ((unsigned)b) << 16;
  return v.f;
}
__device__ __forceinline__ f32x4 mfma16(bf16x8 a, bf16x8 b, f32x4 c) {
  return __builtin_amdgcn_mfma_f32_16x16x32_bf16(a, b, c, 0, 0, 0);
}

// ---------------------------------------------------------------- K0: x [b][c][n] f32 -> xb [b][n][c] bf16
__global__ __launch_bounds__(256) void k_transpose(const float* __restrict__ x,
                                                   unsigned short* __restrict__ xb) {
  __shared__ unsigned short t[64][66];
  const int b = blockIdx.z, k0 = blockIdx.y * 64, n0 = blockIdx.x * 64;
  const float* xp = x + (size_t)b * C_ * HW_;
  const int ln = threadIdx.x & 63, g = threadIdx.x >> 6;
  for (int kk = g; kk < 64; kk += 4)
    t[kk][ln] = f2b(xp[(size_t)(k0 + kk) * HW_ + n0 + ln]);
  __syncthreads();
  unsigned short* xo = xb + (size_t)b * HW_ * C_;
  for (int nn = g; nn < 64; nn += 4)
    xo[(size_t)(n0 + nn) * C_ + k0 + ln] = t[ln][nn];
}

// ---------------------------------------------------------------- K0b: transpose the 4 weight matrices (f32)
__global__ __launch_bounds__(256) void k_wtrans(
    const float* __restrict__ Wq, const float* __restrict__ Wk,
    const float* __restrict__ Wv, const float* __restrict__ Wo,
    float* __restrict__ wt) {
  const float* w; int out, in; float* dst;
  switch (blockIdx.z) {
    case 0: w = Wq; out = 64;  in = 512; dst = wt;          break;
    case 1: w = Wk; out = 64;  in = 512; dst = wt + 32768;  break;
    case 2: w = Wv; out = 256; in = 512; dst = wt + 65536;  break;
    default: w = Wo; out = 512; in = 256; dst = wt + 196608; break;
  }
  const int o0 = blockIdx.y * 64, i0 = blockIdx.x * 64;
  if (o0 >= out || i0 >= in) return;
  __shared__ float t[64][65];
  const int ln = threadIdx.x & 63, g = threadIdx.x >> 6;
  for (int oo = g; oo < 64; oo += 4)
    t[oo][ln] = w[(size_t)(o0 + oo) * in + i0 + ln];
  __syncthreads();
  for (int ii = g; ii < 64; ii += 4)
    dst[(size_t)(i0 + ii) * out + o0 + ln] = t[ln][ii];
}

// ---------------------------------------------------------------- K1: spectral norm, 1024 thr / matrix
__device__ __forceinline__ float breduce1024(float val, float* red) {
  __syncthreads();
#pragma unroll
  for (int off = 32; off > 0; off >>= 1) val += __shfl_down(val, off);
  if ((threadIdx.x & 63) == 0) red[threadIdx.x >> 6] = val;
  __syncthreads();
  float s = 0.f;
#pragma unroll
  for (int i = 0; i < 16; ++i) s += red[i];
  return s;
}

__global__ __launch_bounds__(1024) void k_specnorm(
    const float* __restrict__ Wq, const float* __restrict__ Wk,
    const float* __restrict__ Wv, const float* __restrict__ Wo,
    const float* __restrict__ wt,
    unsigned short* __restrict__ wqkv, unsigned short* __restrict__ wob) {
  __shared__ float u[512], v[512];
  __shared__ float part[4096];
  __shared__ float red[16];
  const float* w; const float* wT; int out, in; unsigned short* dst;
  switch (blockIdx.x) {
    case 0: w = Wq; wT = wt;          out = 64;  in = 512; dst = wqkv;             break;
    case 1: w = Wk; wT = wt + 32768;  out = 64;  in = 512; dst = wqkv + 64 * 512;  break;
    case 2: w = Wv; wT = wt + 65536;  out = 256; in = 512; dst = wqkv + 128 * 512; break;
    default: w = Wo; wT = wt + 196608; out = 512; in = 256; dst = wob;             break;
  }
  const int tid = threadIdx.x;
  const float rs = rsqrtf((float)out);
  if (tid < out) u[tid] = rs;
  __syncthreads();
  for (int it = 0; it < 5; ++it) {
    {
      const int G = in >> 2, nch = 1024 / G;
      const int ch = tid / G, grp = tid - ch * G;
      const int rpc = out / nch, obase = ch * rpc;
      f32x4 acc = {0.f, 0.f, 0.f, 0.f};
#pragma unroll 8
      for (int r = 0; r < rpc; ++r) {
        const int o = obase + r;
        const f32x4 wv = *reinterpret_cast<const f32x4*>(&w[(size_t)o * in + grp * 4]);
        const float uo = u[o];
        acc[0] += wv[0] * uo; acc[1] += wv[1] * uo;
        acc[2] += wv[2] * uo; acc[3] += wv[3] * uo;
      }
      *reinterpret_cast<f32x4*>(&part[ch * in + grp * 4]) = acc;
      __syncthreads();
      if (tid < in) {
        float s = 0.f;
        for (int c2 = 0; c2 < nch; ++c2) s += part[c2 * in + tid];
        v[tid] = s;
      }
    }
    {
      float ss = 0.f;
      __syncthreads();
      if (tid < in) ss = v[tid] * v[tid];
      ss = breduce1024(ss, red);
      const float sv = 1.f / (sqrtf(ss) + 1e-12f);
      if (tid < in) v[tid] *= sv;
      __syncthreads();
    }
    {
      const int G = out >> 2, nch = 1024 / G;
      const int ch = tid / G, grp = tid - ch * G;
      const int cpc = in / nch, cbase = ch * cpc;
      f32x4 acc = {0.f, 0.f, 0.f, 0.f};
#pragma unroll 8
      for (int r = 0; r < cpc; ++r) {
        const int c = cbase + r;
        const f32x4 wv = *reinterpret_cast<const f32x4*>(&wT[(size_t)c * out + grp * 4]);
        const float vc = v[c];
        acc[0] += wv[0] * vc; acc[1] += wv[1] * vc;
        acc[2] += wv[2] * vc; acc[3] += wv[3] * vc;
      }
      *reinterpret_cast<f32x4*>(&part[ch * out + grp * 4]) = acc;
      __syncthreads();
      if (tid < out) {
        float s = 0.f;
        for (int c2 = 0; c2 < nch; ++c2) s += part[c2 * out + tid];
        u[tid] = s;
      }
    }
    {
      float su = 0.f;
      __syncthreads();
      if (tid < out) su = u[tid] * u[tid];
      su = breduce1024(su, red);
      const float sv2 = 1.f / (sqrtf(su) + 1e-12f);
      if (tid < out) u[tid] *= sv2;
      __syncthreads();
    }
  }
  float sp = 0.f;
  {
    const int G = out >> 2, nch = 1024 / G;
    const int ch = tid / G, grp = tid - ch * G;
    const int cpc = in / nch, cbase = ch * cpc;
    f32x4 acc = {0.f, 0.f, 0.f, 0.f};
#pragma unroll 8
    for (int r = 0; r < cpc; ++r) {
      const int c = cbase + r;
      const f32x4 wv = *reinterpret_cast<const f32x4*>(&wT[(size_t)c * out + grp * 4]);
      const float vc = v[c];
      acc[0] += wv[0] * vc; acc[1] += wv[1] * vc;
      acc[2] += wv[2] * vc; acc[3] += wv[3] * vc;
    }
    *reinterpret_cast<f32x4*>(&part[ch * out + grp * 4]) = acc;
    __syncthreads();
    if (tid < out) {
      float s = 0.f;
      for (int c2 = 0; c2 < nch; ++c2) s += part[c2 * out + tid];
      sp = s * u[tid];
    }
  }
  sp = breduce1024(sp, red);
  const float oscale = (blockIdx.x == 0) ? 1.44269504f : 1.0f;
  const float inv_sigma = (1.f / sp) * oscale;
  const int total = out * in;
  for (int i = tid * 4; i < total; i += 4096) {
    const f32x4 wv = *reinterpret_cast<const f32x4*>(&w[i]);
    u32x2 pw;
    pw[0] = ((unsigned)f2b(wv[1] * inv_sigma) << 16) | f2b(wv[0] * inv_sigma);
    pw[1] = ((unsigned)f2b(wv[3] * inv_sigma) << 16) | f2b(wv[2] * inv_sigma);
    *reinterpret_cast<u32x2*>(&dst[i]) = pw;
  }
}

// ---------------------------------------------------------------- K2: Yt[b][n][m] = xb[b][n][k] * wqkv[m][k]
__global__ __launch_bounds__(256) void k_gemm_qkv(
    const unsigned short* __restrict__ xb, const unsigned short* __restrict__ wqkv,
    unsigned short* __restrict__ yt) {
  __shared__ alignas(16) char smem[32768];
  unsigned short* As = (unsigned short*)smem;
  unsigned short* Bs = (unsigned short*)(smem + 16384);
  const int lid = blockIdx.x;
  const int swz = (lid & 7) * 192 + (lid >> 3);
  const int mt = swz % 3, rest = swz / 3;
  const int nt = rest & 31, b = rest >> 5;
  const int n0 = nt * 128, m0 = mt * 128;
  const unsigned short* Ap = xb + (size_t)b * HW_ * C_ + (size_t)n0 * C_;
  const unsigned short* Bp = wqkv + (size_t)m0 * C_;
  const int tid = threadIdx.x, lane = tid & 63, wid = tid >> 6;
  const int wn = (wid >> 1) * 64, wm = (wid & 1) * 64;
  f32x4 acc[4][4] = {};
  for (int k0 = 0; k0 < C_; k0 += 64) {
    __syncthreads();
#pragma unroll
    for (int i = 0; i < 4; ++i) {
      const int r = i * 32 + (tid >> 3);
      const int s = tid & 7, ss = s ^ (r & 7);
      *reinterpret_cast<f32x4*>(&As[r * 64 + ss * 8]) =
          *reinterpret_cast<const f32x4*>(&Ap[(size_t)r * C_ + k0 + s * 8]);
      *reinterpret_cast<f32x4*>(&Bs[r * 64 + ss * 8]) =
          *reinterpret_cast<const f32x4*>(&Bp[(size_t)r * C_ + k0 + s * 8]);
    }
    __syncthreads();
#pragma unroll
    for (int kk = 0; kk < 2; ++kk) {
      bf16x8 af[4], bfr[4];
#pragma unroll
      for (int i = 0; i < 4; ++i) {
        const int r = wn + i * 16 + (lane & 15);
        const int slot = (kk * 4 + (lane >> 4)) ^ (r & 7);
        af[i] = *reinterpret_cast<const bf16x8*>(&As[r * 64 + slot * 8]);
      }
#pragma unroll
      for (int j = 0; j < 4; ++j) {
        const int r = wm + j * 16 + (lane & 15);
        const int slot = (kk * 4 + (lane >> 4)) ^ (r & 7);
        bfr[j] = *reinterpret_cast<const bf16x8*>(&Bs[r * 64 + slot * 8]);
      }
#pragma unroll
      for (int i = 0; i < 4; ++i)
#pragma unroll
        for (int j = 0; j < 4; ++j) acc[i][j] = mfma16(af[i], bfr[j], acc[i][j]);
    }
  }
  unsigned short* eps = (unsigned short*)smem;
  unsigned short* Y = yt + (size_t)b * HW_ * M3_;
#pragma unroll
  for (int h = 0; h < 2; ++h) {
    __syncthreads();
    if ((wid >> 1) == h) {
#pragma unroll
      for (int i = 0; i < 4; ++i)
#pragma unroll
        for (int j = 0; j < 4; ++j)
#pragma unroll
          for (int r = 0; r < 4; ++r) {
            const int nl = i * 16 + (lane >> 4) * 4 + r;
            const int ml = wm + j * 16 + (lane & 15);
            eps[nl * 136 + ml] = f2b(acc[i][j][r]);
          }
    }
    __syncthreads();
#pragma unroll
    for (int t = 0; t < 4; ++t) {
      const int row = t * 16 + (tid >> 4);
      const int m8 = (tid & 15) * 8;
      *reinterpret_cast<f32x4*>(&Y[(size_t)(n0 + h * 64 + row) * M3_ + m0 + m8]) =
          *reinterpret_cast<const f32x4*>(&eps[row * 136 + m8]);
    }
  }
}

// ---------------------------------------------------------------- K3a: gt[b][mp][c] = maxpool(Yt cols 64..127)
__global__ __launch_bounds__(256) void k_pool_g(const unsigned short* __restrict__ yt,
                                                unsigned short* __restrict__ gt) {
  const int b = blockIdx.y, mp0 = blockIdx.x * 64;
  const int c = threadIdx.x & 63, dm = threadIdx.x >> 6;
  const unsigned short* Y = yt + (size_t)b * HW_ * M3_;
  unsigned short* G = gt + (size_t)b * HWP_ * 64;
  for (int mm = dm; mm < 64; mm += 4) {
    const int mp = mp0 + mm;
    const int n00 = (mp >> 5) * 128 + (mp & 31) * 2;
    const float a0 = b2f(Y[(size_t)n00 * M3_ + 64 + c]);
    const float a1 = b2f(Y[(size_t)(n00 + 1) * M3_ + 64 + c]);
    const float a2 = b2f(Y[(size_t)(n00 + 64) * M3_ + 64 + c]);
    const float a3 = b2f(Y[(size_t)(n00 + 65) * M3_ + 64 + c]);
    G[(size_t)mp * 64 + c] = f2b(fmaxf(fmaxf(a0, a1), fmaxf(a2, a3)));
  }
}

// ---------------------------------------------------------------- K3b: vt[b][cv][mp] = maxpool(Yt cols 128..383)^T
__global__ __launch_bounds__(256) void k_pool_vt(const unsigned short* __restrict__ yt,
                                                 unsigned short* __restrict__ vt) {
  __shared__ unsigned short t[64][66];
  const int b = blockIdx.z, mp0 = blockIdx.x * 64, cv0 = blockIdx.y * 64;
  const unsigned short* Y = yt + (size_t)b * HW_ * M3_;
  const int c = threadIdx.x & 63, dm = threadIdx.x >> 6;
  for (int mm = dm; mm < 64; mm += 4) {
    const int mp = mp0 + mm;
    const int n00 = (mp >> 5) * 128 + (mp & 31) * 2;
    const float a0 = b2f(Y[(size_t)n00 * M3_ + 128 + cv0 + c]);
    const float a1 = b2f(Y[(size_t)(n00 + 1) * M3_ + 128 + cv0 + c]);
    const float a2 = b2f(Y[(size_t)(n00 + 64) * M3_ + 128 + cv0 + c]);
    const float a3 = b2f(Y[(size_t)(n00 + 65) * M3_ + 128 + cv0 + c]);
    t[mm][c] = f2b(fmaxf(fmaxf(a0, a1), fmaxf(a2, a3)));
  }
  __syncthreads();
  unsigned short* V = vt + (size_t)b * CV_ * HWP_;
  for (int cc = dm; cc < 64; cc += 4)
    V[(size_t)(cv0 + cc) * HWP_ + mp0 + c] = t[c][cc];
}

// ---------------------------------------------------------------- K4: flash attention, 4 waves x 32q = 128q/block
// LDS-staged K/V (R8-proven); each wave handles TWO 16-q groups so the K/V
// fragment reads amortize 2x (kf shared across groups, each vf feeds 2 MFMAs).
// P wave-private in LDS (no cross-wave sharing, no extra barrier).
__global__ __launch_bounds__(256, 2) void k_attn(
    const unsigned short* __restrict__ yt, const unsigned short* __restrict__ gt,
    const unsigned short* __restrict__ vt, unsigned short* __restrict__ oat) {
  __shared__ alignas(16) char smem[57344];
  unsigned short* Ks = (unsigned short*)smem;              // 8KB  [64][64]
  unsigned short* Vs = (unsigned short*)(smem + 8192);     // 32KB [256][64]
  unsigned short* Ps = (unsigned short*)(smem + 40960);    // 16KB 4 x [32][64]
  const int lid = blockIdx.x;                              // 512 blocks
  const int swz = (lid & 7) * 64 + (lid >> 3);
  const int q0 = (swz & 31) * 128, b = swz >> 5;
  const int tid = threadIdx.x, lane = tid & 63, wid = tid >> 6;  // 4 waves
  const int q = lane & 15, g = lane >> 4;
  const unsigned short* Qg = yt + (size_t)b * HW_ * M3_ + (size_t)(q0 + wid * 32) * M3_;
  const unsigned short* Gg = gt + (size_t)b * HWP_ * 64;
  const unsigned short* Vg = vt + (size_t)b * CV_ * HWP_;
  unsigned short* P = Ps + wid * 2048;                     // 32 q-rows x 64 kv
  // Q fragments: two 16-q groups, direct global->regs, kept all kernel
  bf16x8 qf[2][2];
#pragma unroll
  for (int h = 0; h < 2; ++h)
#pragma unroll
    for (int kk = 0; kk < 2; ++kk)
      qf[h][kk] = *reinterpret_cast<const bf16x8*>(&Qg[(size_t)(h * 16 + q) * M3_ + kk * 32 + g * 8]);
  // prologue: K/V tile 0 -> regs (256 threads: K 2 chunks, V 8 chunks)
  f32x4 kreg[2], vreg[8];
#pragma unroll
  for (int t = 0; t < 2; ++t) {
    const int i = tid + t * 256, r = i >> 3, s = i & 7;
    kreg[t] = *reinterpret_cast<const f32x4*>(&Gg[(size_t)r * 64 + s * 8]);
  }
#pragma unroll
  for (int t = 0; t < 8; ++t) {
    const int i = tid + t * 256, r = i >> 3, s = i & 7;
    vreg[t] = *reinterpret_cast<const f32x4*>(&Vg[(size_t)r * HWP_ + s * 8]);
  }
  f32x4 oacc[2][16] = {};
  float m_run[2] = {-1e30f, -1e30f}, l_run[2] = {0.f, 0.f};
  for (int it = 0; it < 16; ++it) {
    __syncthreads();
#pragma unroll
    for (int t = 0; t < 2; ++t) {
      const int i = tid + t * 256, r = i >> 3, s = i & 7, ss = s ^ (r & 7);
      *reinterpret_cast<f32x4*>(&Ks[r * 64 + ss * 8]) = kreg[t];
    }
#pragma unroll
    for (int t = 0; t < 8; ++t) {
      const int i = tid + t * 256, r = i >> 3, s = i & 7, ss = s ^ (r & 7);
      *reinterpret_cast<f32x4*>(&Vs[r * 64 + ss * 8]) = vreg[t];
    }
    __syncthreads();
    if (it < 15) {  // prefetch next tile; consumed next iteration
      const int kvn = (it + 1) * 64;
#pragma unroll
      for (int t = 0; t < 2; ++t) {
        const int i = tid + t * 256, r = i >> 3, s = i & 7;
        kreg[t] = *reinterpret_cast<const f32x4*>(&Gg[(size_t)(kvn + r) * 64 + s * 8]);
      }
#pragma unroll
      for (int t = 0; t < 8; ++t) {
        const int i = tid + t * 256, r = i >> 3, s = i & 7;
        vreg[t] = *reinterpret_cast<const f32x4*>(&Vg[(size_t)r * HWP_ + kvn + s * 8]);
      }
    }
    // QK^T (swapped): kf read once per kk, shared across both q-groups
    f32x4 sacc[2][4] = {};
#pragma unroll
    for (int kk = 0; kk < 2; ++kk) {
      bf16x8 kf[4];
#pragma unroll
      for (int i = 0; i < 4; ++i) {
        const int row = i * 16 + q;
        const int sl = (kk * 4 + g) ^ (row & 7);
        kf[i] = *reinterpret_cast<const bf16x8*>(&Ks[row * 64 + sl * 8]);
      }
#pragma unroll
      for (int h = 0; h < 2; ++h)
#pragma unroll
        for (int i = 0; i < 4; ++i) sacc[h][i] = mfma16(kf[i], qf[h][kk], sacc[h][i]);
    }
    // online softmax per q-group (log2 domain, defer-max, per-wave)
#pragma unroll
    for (int h = 0; h < 2; ++h) {
      float tmax = -1e30f;
#pragma unroll
      for (int i = 0; i < 4; ++i)
#pragma unroll
        for (int r = 0; r < 4; ++r) tmax = fmaxf(tmax, sacc[h][i][r]);
      tmax = fmaxf(tmax, __shfl_xor(tmax, 16));
      tmax = fmaxf(tmax, __shfl_xor(tmax, 32));
      if (__any(tmax > m_run[h] + 11.0f)) {
        const float mnew = fmaxf(m_run[h], tmax);
        const float alpha = exp2f(m_run[h] - mnew);
        m_run[h] = mnew;
        l_run[h] *= alpha;
        float al[4];
#pragma unroll
        for (int r = 0; r < 4; ++r) al[r] = __shfl(alpha, g * 4 + r);
#pragma unroll
        for (int j = 0; j < 16; ++j) {
          oacc[h][j][0] *= al[0]; oacc[h][j][1] *= al[1];
          oacc[h][j][2] *= al[2]; oacc[h][j][3] *= al[3];
        }
      }
      const int qg = h * 16 + q;
      float lsum = 0.f;
#pragma unroll
      for (int i = 0; i < 4; ++i) {
        const float p0 = exp2f(sacc[h][i][0] - m_run[h]);
        const float p1 = exp2f(sacc[h][i][1] - m_run[h]);
        const float p2 = exp2f(sacc[h][i][2] - m_run[h]);
        const float p3 = exp2f(sacc[h][i][3] - m_run[h]);
        lsum += (p0 + p1) + (p2 + p3);
        u32x2 pw;
        pw[0] = ((unsigned)f2b(p1) << 16) | f2b(p0);
        pw[1] = ((unsigned)f2b(p3) << 16) | f2b(p2);
        const int sl = (2 * i + (g >> 1)) ^ (qg & 7);   // (kv>>3) ^ (row&7)
        *reinterpret_cast<u32x2*>(&P[qg * 64 + sl * 8 + (g & 1) * 4]) = pw;
      }
      lsum += __shfl_xor(lsum, 16);
      lsum += __shfl_xor(lsum, 32);
      l_run[h] += lsum;
    }
    // PV: pa per group from wave-private P; each vf read feeds both groups
    __builtin_amdgcn_s_setprio(1);
#pragma unroll
    for (int kk = 0; kk < 2; ++kk) {
      bf16x8 pa[2];
#pragma unroll
      for (int h = 0; h < 2; ++h)
        pa[h] = *reinterpret_cast<const bf16x8*>(
            &P[(h * 16 + q) * 64 + (((kk * 4 + g) ^ (q & 7))) * 8]);
#pragma unroll
      for (int j = 0; j < 16; ++j) {
        const int row = j * 16 + q;
        const int sl = (kk * 4 + g) ^ (row & 7);
        const bf16x8 vf = *reinterpret_cast<const bf16x8*>(&Vs[row * 64 + sl * 8]);
        oacc[0][j] = mfma16(pa[0], vf, oacc[0][j]);
        oacc[1][j] = mfma16(pa[1], vf, oacc[1][j]);
      }
    }
    __builtin_amdgcn_s_setprio(0);
  }
  // epilogue: normalize, repack 2 chunks of 64 rows, dwordx4 store
  float linv[2][4];
#pragma unroll
  for (int h = 0; h < 2; ++h) {
    const float myinv = 1.f / l_run[h];
#pragma unroll
    for (int r = 0; r < 4; ++r) linv[h][r] = __shfl(myinv, g * 4 + r);
  }
  unsigned short* eps = (unsigned short*)smem;   // 64 x 264 bf16 = 33792B
  unsigned short* O = oat + (size_t)b * HW_ * CV_ + (size_t)q0 * CV_;
#pragma unroll
  for (int ch = 0; ch < 2; ++ch) {
    __syncthreads();
    if ((wid >> 1) == ch) {
#pragma unroll
      for (int h = 0; h < 2; ++h)
#pragma unroll
        for (int j = 0; j < 16; ++j)
#pragma unroll
          for (int r = 0; r < 4; ++r) {
            const int row = (wid & 1) * 32 + h * 16 + g * 4 + r;
            const int cv = j * 16 + q;
            eps[row * 264 + cv] = f2b(oacc[h][j][r] * linv[h][r]);
          }
    }
    __syncthreads();
#pragma unroll
    for (int t = 0; t < 8; ++t) {
      const int row = t * 8 + (tid >> 5);
      const int cv8 = (tid & 31) * 8;
      *reinterpret_cast<f32x4*>(&O[(size_t)(ch * 64 + row) * CV_ + cv8]) =
          *reinterpret_cast<const f32x4*>(&eps[row * 264 + cv8]);
    }
  }
}

// ---------------------------------------------------------------- K5: out[b][co][n] = gamma * wo@Oatt^T + x
__global__ __launch_bounds__(256) void k_gemm_out(
    const unsigned short* __restrict__ oat, const unsigned short* __restrict__ wob,
    const float* __restrict__ x, const float* __restrict__ gamma,
    float* __restrict__ out) {
  __shared__ alignas(16) char smem[32768];
  unsigned short* As = (unsigned short*)smem;
  unsigned short* Bs = (unsigned short*)(smem + 16384);
  const int lid = blockIdx.x;
  const int swz = (lid & 7) * 256 + (lid >> 3);
  const int ct = swz & 3, nt = (swz >> 2) & 31, b = swz >> 7;
  const int n0 = nt * 128, co0 = ct * 128;
  const unsigned short* Ap = wob + (size_t)co0 * CV_;
  const unsigned short* Bp = oat + (size_t)b * HW_ * CV_ + (size_t)n0 * CV_;
  const int tid = threadIdx.x, lane = tid & 63, wid = tid >> 6;
  const int wc = (wid >> 1) * 64, wn = (wid & 1) * 64;
  f32x4 acc[4][4] = {};
  for (int k0 = 0; k0 < CV_; k0 += 64) {
    __syncthreads();
#pragma unroll
    for (int i = 0; i < 4; ++i) {
      const int r = i * 32 + (tid >> 3);
      const int s = tid & 7, ss = s ^ (r & 7);
      *reinterpret_cast<f32x4*>(&As[r * 64 + ss * 8]) =
          *reinterpret_cast<const f32x4*>(&Ap[(size_t)r * CV_ + k0 + s * 8]);
      *reinterpret_cast<f32x4*>(&Bs[r * 64 + ss * 8]) =
          *reinterpret_cast<const f32x4*>(&Bp[(size_t)r * CV_ + k0 + s * 8]);
    }
    __syncthreads();
#pragma unroll
    for (int kk = 0; kk < 2; ++kk) {
      bf16x8 af[4], bfr[4];
#pragma unroll
      for (int i = 0; i < 4; ++i) {
        const int r = wc + i * 16 + (lane & 15);
        const int slot = (kk * 4 + (lane >> 4)) ^ (r & 7);
        af[i] = *reinterpret_cast<const bf16x8*>(&As[r * 64 + slot * 8]);
      }
#pragma unroll
      for (int j = 0; j < 4; ++j) {
        const int r = wn + j * 16 + (lane & 15);
        const int slot = (kk * 4 + (lane >> 4)) ^ (r & 7);
        bfr[j] = *reinterpret_cast<const bf16x8*>(&Bs[r * 64 + slot * 8]);
      }
#pragma unroll
      for (int i = 0; i < 4; ++i)
#pragma unroll
        for (int j = 0; j < 4; ++j) acc[i][j] = mfma16(af[i], bfr[j], acc[i][j]);
    }
  }
  float* eps = (float*)smem;
  const float g = gamma[0];
  const size_t base = (size_t)b * C_ * HW_;
#pragma unroll
  for (int h = 0; h < 4; ++h) {
    __syncthreads();
    if ((wid >> 1) == (h >> 1)) {
#pragma unroll
      for (int ii = 0; ii < 2; ++ii) {
        const int i = (h & 1) * 2 + ii;
#pragma unroll
        for (int j = 0; j < 4; ++j)
#pragma unroll
          for (int r = 0; r < 4; ++r) {
            const int col2 = ii * 16 + (lane >> 4) * 4 + r;
            const int nl = wn + j * 16 + (lane & 15);
            eps[col2 * 132 + nl] = acc[i][j][r];
          }
      }
    }
    __syncthreads();
#pragma unroll
    for (int t = 0; t < 4; ++t) {
      const int row = t * 8 + (tid >> 5);
      const int col = (tid & 31) * 4;
      const size_t goff = base + (size_t)(co0 + h * 32 + row) * HW_ + n0 + col;
      const f32x4 xv = *reinterpret_cast<const f32x4*>(&x[goff]);
      const f32x4 av = *reinterpret_cast<const f32x4*>(&eps[row * 132 + col]);
      f32x4 ov;
      ov[0] = g * av[0] + xv[0];
      ov[1] = g * av[1] + xv[1];
      ov[2] = g * av[2] + xv[2];
      ov[3] = g * av[3] + xv[3];
      *reinterpret_cast<f32x4*>(&out[goff]) = ov;
    }
  }
}

// ---------------------------------------------------------------- launcher
extern "C" void kernel_launch(void* const* d_in, const int* in_sizes, int n_in,
                              void* d_out, int out_size, void* d_ws, size_t ws_size,
                              hipStream_t stream) {
  (void)in_sizes; (void)n_in; (void)out_size; (void)ws_size;
  const float* x     = (const float*)d_in[0];
  const float* Wq    = (const float*)d_in[1];
  const float* Wk    = (const float*)d_in[2];
  const float* Wv    = (const float*)d_in[3];
  const float* Wo    = (const float*)d_in[4];
  const float* gamma = (const float*)d_in[5];
  float* out = (float*)d_out;
  char* ws = (char*)d_ws;

  unsigned short* wqkv = (unsigned short*)(ws);                 // 384*512*2
  unsigned short* wob  = (unsigned short*)(ws + 393216);        // 512*256*2
  unsigned short* xb   = (unsigned short*)(ws + 655360);        // 64MB
  unsigned short* yt   = (unsigned short*)(ws + 67764224);      // 48MB
  unsigned short* gt   = (unsigned short*)(ws + 118095872);     // 2MB
  unsigned short* vt   = (unsigned short*)(ws + 120193024);     // 8MB
  unsigned short* oat  = xb;   // alias: xb dead after k_gemm_qkv
  float* wt = (float*)yt;      // alias: wT only live during specnorm (yt written later)

  k_transpose<<<dim3(64, 8, 16), 256, 0, stream>>>(x, xb);
  k_wtrans<<<dim3(8, 8, 4), 256, 0, stream>>>(Wq, Wk, Wv, Wo, wt);
  k_specnorm<<<4, 1024, 0, stream>>>(Wq, Wk, Wv, Wo, wt, wqkv, wob);
  k_gemm_qkv<<<1536, 256, 0, stream>>>(xb, wqkv, yt);
  k_pool_g<<<dim3(16, 16), 256, 0, stream>>>(yt, gt);
  k_pool_vt<<<dim3(16, 4, 16), 256, 0, stream>>>(yt, vt);
  k_attn<<<512, 256, 0, stream>>>(yt, gt, vt, oat);
  k_gemm_out<<<2048, 256, 0, stream>>>(oat, wob, x, gamma, out);
}

// Round 11
// 296.284 us; speedup vs baseline: 1.6092x; 1.0928x over previous
//
#include <hip/hip_runtime.h>
#include <cstdint>

typedef __attribute__((ext_vector_type(8))) short bf16x8;
typedef __attribute__((ext_vector_type(4))) float f32x4;
typedef __attribute__((ext_vector_type(2))) unsigned int u32x2;

#define B_   16
#define C_   512
#define HW_  4096
#define M3_  384
#define HWP_ 1024
#define CV_  256

__device__ __forceinline__ unsigned short f2b(float f) {
  union { float f; unsigned u; } v; v.f = f;
  unsigned r = v.u + 0x7fffu + ((v.u >> 16) & 1u);   // RNE
  return (unsigned short)(r >> 16);
}
__device__ __forceinline__ float b2f(unsigned short b) {
  union { unsigned u; float f; } v; v.u = ((unsigned)b) << 16;
  return v.f;
}
__device__ __forceinline__ f32x4 mfma16(bf16x8 a, bf16x8 b, f32x4 c) {
  return __builtin_amdgcn_mfma_f32_16x16x32_bf16(a, b, c, 0, 0, 0);
}

// ---------------------------------------------------------------- K0: x [b][c][n] f32 -> xb [b][n][c] bf16
__global__ __launch_bounds__(256) void k_transpose(const float* __restrict__ x,
                                                   unsigned short* __restrict__ xb) {
  __shared__ unsigned short t[64][66];
  const int b = blockIdx.z, k0 = blockIdx.y * 64, n0 = blockIdx.x * 64;
  const float* xp = x + (size_t)b * C_ * HW_;
  const int ln = threadIdx.x & 63, g = threadIdx.x >> 6;
  for (int kk = g; kk < 64; kk += 4)
    t[kk][ln] = f2b(xp[(size_t)(k0 + kk) * HW_ + n0 + ln]);
  __syncthreads();
  unsigned short* xo = xb + (size_t)b * HW_ * C_;
  for (int nn = g; nn < 64; nn += 4)
    xo[(size_t)(n0 + nn) * C_ + k0 + ln] = t[ln][nn];
}

// ---------------------------------------------------------------- K0b: transpose the 4 weight matrices (f32)
__global__ __launch_bounds__(256) void k_wtrans(
    const float* __restrict__ Wq, const float* __restrict__ Wk,
    const float* __restrict__ Wv, const float* __restrict__ Wo,
    float* __restrict__ wt) {
  const float* w; int out, in; float* dst;
  switch (blockIdx.z) {
    case 0: w = Wq; out = 64;  in = 512; dst = wt;          break;
    case 1: w = Wk; out = 64;  in = 512; dst = wt + 32768;  break;
    case 2: w = Wv; out = 256; in = 512; dst = wt + 65536;  break;
    default: w = Wo; out = 512; in = 256; dst = wt + 196608; break;
  }
  const int o0 = blockIdx.y * 64, i0 = blockIdx.x * 64;
  if (o0 >= out || i0 >= in) return;
  __shared__ float t[64][65];
  const int ln = threadIdx.x & 63, g = threadIdx.x >> 6;
  for (int oo = g; oo < 64; oo += 4)
    t[oo][ln] = w[(size_t)(o0 + oo) * in + i0 + ln];
  __syncthreads();
  for (int ii = g; ii < 64; ii += 4)
    dst[(size_t)(i0 + ii) * out + o0 + ln] = t[ln][ii];
}

// ---------------------------------------------------------------- K1: spectral norm, 1024 thr / matrix
__device__ __forceinline__ float breduce1024(float val, float* red) {
  __syncthreads();
#pragma unroll
  for (int off = 32; off > 0; off >>= 1) val += __shfl_down(val, off);
  if ((threadIdx.x & 63) == 0) red[threadIdx.x >> 6] = val;
  __syncthreads();
  float s = 0.f;
#pragma unroll
  for (int i = 0; i < 16; ++i) s += red[i];
  return s;
}

__global__ __launch_bounds__(1024) void k_specnorm(
    const float* __restrict__ Wq, const float* __restrict__ Wk,
    const float* __restrict__ Wv, const float* __restrict__ Wo,
    const float* __restrict__ wt,
    unsigned short* __restrict__ wqkv, unsigned short* __restrict__ wob) {
  __shared__ float u[512], v[512];
  __shared__ float part[4096];
  __shared__ float red[16];
  const float* w; const float* wT; int out, in; unsigned short* dst;
  switch (blockIdx.x) {
    case 0: w = Wq; wT = wt;          out = 64;  in = 512; dst = wqkv;             break;
    case 1: w = Wk; wT = wt + 32768;  out = 64;  in = 512; dst = wqkv + 64 * 512;  break;
    case 2: w = Wv; wT = wt + 65536;  out = 256; in = 512; dst = wqkv + 128 * 512; break;
    default: w = Wo; wT = wt + 196608; out = 512; in = 256; dst = wob;             break;
  }
  const int tid = threadIdx.x;
  const float rs = rsqrtf((float)out);
  if (tid < out) u[tid] = rs;
  __syncthreads();
  for (int it = 0; it < 5; ++it) {
    {
      const int G = in >> 2, nch = 1024 / G;
      const int ch = tid / G, grp = tid - ch * G;
      const int rpc = out / nch, obase = ch * rpc;
      f32x4 acc = {0.f, 0.f, 0.f, 0.f};
#pragma unroll 8
      for (int r = 0; r < rpc; ++r) {
        const int o = obase + r;
        const f32x4 wv = *reinterpret_cast<const f32x4*>(&w[(size_t)o * in + grp * 4]);
        const float uo = u[o];
        acc[0] += wv[0] * uo; acc[1] += wv[1] * uo;
        acc[2] += wv[2] * uo; acc[3] += wv[3] * uo;
      }
      *reinterpret_cast<f32x4*>(&part[ch * in + grp * 4]) = acc;
      __syncthreads();
      if (tid < in) {
        float s = 0.f;
        for (int c2 = 0; c2 < nch; ++c2) s += part[c2 * in + tid];
        v[tid] = s;
      }
    }
    {
      float ss = 0.f;
      __syncthreads();
      if (tid < in) ss = v[tid] * v[tid];
      ss = breduce1024(ss, red);
      const float sv = 1.f / (sqrtf(ss) + 1e-12f);
      if (tid < in) v[tid] *= sv;
      __syncthreads();
    }
    {
      const int G = out >> 2, nch = 1024 / G;
      const int ch = tid / G, grp = tid - ch * G;
      const int cpc = in / nch, cbase = ch * cpc;
      f32x4 acc = {0.f, 0.f, 0.f, 0.f};
#pragma unroll 8
      for (int r = 0; r < cpc; ++r) {
        const int c = cbase + r;
        const f32x4 wv = *reinterpret_cast<const f32x4*>(&wT[(size_t)c * out + grp * 4]);
        const float vc = v[c];
        acc[0] += wv[0] * vc; acc[1] += wv[1] * vc;
        acc[2] += wv[2] * vc; acc[3] += wv[3] * vc;
      }
      *reinterpret_cast<f32x4*>(&part[ch * out + grp * 4]) = acc;
      __syncthreads();
      if (tid < out) {
        float s = 0.f;
        for (int c2 = 0; c2 < nch; ++c2) s += part[c2 * out + tid];
        u[tid] = s;
      }
    }
    {
      float su = 0.f;
      __syncthreads();
      if (tid < out) su = u[tid] * u[tid];
      su = breduce1024(su, red);
      const float sv2 = 1.f / (sqrtf(su) + 1e-12f);
      if (tid < out) u[tid] *= sv2;
      __syncthreads();
    }
  }
  float sp = 0.f;
  {
    const int G = out >> 2, nch = 1024 / G;
    const int ch = tid / G, grp = tid - ch * G;
    const int cpc = in / nch, cbase = ch * cpc;
    f32x4 acc = {0.f, 0.f, 0.f, 0.f};
#pragma unroll 8
    for (int r = 0; r < cpc; ++r) {
      const int c = cbase + r;
      const f32x4 wv = *reinterpret_cast<const f32x4*>(&wT[(size_t)c * out + grp * 4]);
      const float vc = v[c];
      acc[0] += wv[0] * vc; acc[1] += wv[1] * vc;
      acc[2] += wv[2] * vc; acc[3] += wv[3] * vc;
    }
    *reinterpret_cast<f32x4*>(&part[ch * out + grp * 4]) = acc;
    __syncthreads();
    if (tid < out) {
      float s = 0.f;
      for (int c2 = 0; c2 < nch; ++c2) s += part[c2 * out + tid];
      sp = s * u[tid];
    }
  }
  sp = breduce1024(sp, red);
  const float oscale = (blockIdx.x == 0) ? 1.44269504f : 1.0f;
  const float inv_sigma = (1.f / sp) * oscale;
  const int total = out * in;
  for (int i = tid * 4; i < total; i += 4096) {
    const f32x4 wv = *reinterpret_cast<const f32x4*>(&w[i]);
    u32x2 pw;
    pw[0] = ((unsigned)f2b(wv[1] * inv_sigma) << 16) | f2b(wv[0] * inv_sigma);
    pw[1] = ((unsigned)f2b(wv[3] * inv_sigma) << 16) | f2b(wv[2] * inv_sigma);
    *reinterpret_cast<u32x2*>(&dst[i]) = pw;
  }
}

// ---------------------------------------------------------------- K2: Yt[b][n][m] = xb[b][n][k] * wqkv[m][k]
__global__ __launch_bounds__(256) void k_gemm_qkv(
    const unsigned short* __restrict__ xb, const unsigned short* __restrict__ wqkv,
    unsigned short* __restrict__ yt) {
  __shared__ alignas(16) char smem[32768];
  unsigned short* As = (unsigned short*)smem;
  unsigned short* Bs = (unsigned short*)(smem + 16384);
  const int lid = blockIdx.x;
  const int swz = (lid & 7) * 192 + (lid >> 3);
  const int mt = swz % 3, rest = swz / 3;
  const int nt = rest & 31, b = rest >> 5;
  const int n0 = nt * 128, m0 = mt * 128;
  const unsigned short* Ap = xb + (size_t)b * HW_ * C_ + (size_t)n0 * C_;
  const unsigned short* Bp = wqkv + (size_t)m0 * C_;
  const int tid = threadIdx.x, lane = tid & 63, wid = tid >> 6;
  const int wn = (wid >> 1) * 64, wm = (wid & 1) * 64;
  f32x4 acc[4][4] = {};
  for (int k0 = 0; k0 < C_; k0 += 64) {
    __syncthreads();
#pragma unroll
    for (int i = 0; i < 4; ++i) {
      const int r = i * 32 + (tid >> 3);
      const int s = tid & 7, ss = s ^ (r & 7);
      *reinterpret_cast<f32x4*>(&As[r * 64 + ss * 8]) =
          *reinterpret_cast<const f32x4*>(&Ap[(size_t)r * C_ + k0 + s * 8]);
      *reinterpret_cast<f32x4*>(&Bs[r * 64 + ss * 8]) =
          *reinterpret_cast<const f32x4*>(&Bp[(size_t)r * C_ + k0 + s * 8]);
    }
    __syncthreads();
#pragma unroll
    for (int kk = 0; kk < 2; ++kk) {
      bf16x8 af[4], bfr[4];
#pragma unroll
      for (int i = 0; i < 4; ++i) {
        const int r = wn + i * 16 + (lane & 15);
        const int slot = (kk * 4 + (lane >> 4)) ^ (r & 7);
        af[i] = *reinterpret_cast<const bf16x8*>(&As[r * 64 + slot * 8]);
      }
#pragma unroll
      for (int j = 0; j < 4; ++j) {
        const int r = wm + j * 16 + (lane & 15);
        const int slot = (kk * 4 + (lane >> 4)) ^ (r & 7);
        bfr[j] = *reinterpret_cast<const bf16x8*>(&Bs[r * 64 + slot * 8]);
      }
#pragma unroll
      for (int i = 0; i < 4; ++i)
#pragma unroll
        for (int j = 0; j < 4; ++j) acc[i][j] = mfma16(af[i], bfr[j], acc[i][j]);
    }
  }
  unsigned short* eps = (unsigned short*)smem;
  unsigned short* Y = yt + (size_t)b * HW_ * M3_;
#pragma unroll
  for (int h = 0; h < 2; ++h) {
    __syncthreads();
    if ((wid >> 1) == h) {
#pragma unroll
      for (int i = 0; i < 4; ++i)
#pragma unroll
        for (int j = 0; j < 4; ++j)
#pragma unroll
          for (int r = 0; r < 4; ++r) {
            const int nl = i * 16 + (lane >> 4) * 4 + r;
            const int ml = wm + j * 16 + (lane & 15);
            eps[nl * 136 + ml] = f2b(acc[i][j][r]);
          }
    }
    __syncthreads();
#pragma unroll
    for (int t = 0; t < 4; ++t) {
      const int row = t * 16 + (tid >> 4);
      const int m8 = (tid & 15) * 8;
      *reinterpret_cast<f32x4*>(&Y[(size_t)(n0 + h * 64 + row) * M3_ + m0 + m8]) =
          *reinterpret_cast<const f32x4*>(&eps[row * 136 + m8]);
    }
  }
}

// ---------------------------------------------------------------- K3a: gt[b][mp][c] = maxpool(Yt cols 64..127)
__global__ __launch_bounds__(256) void k_pool_g(const unsigned short* __restrict__ yt,
                                                unsigned short* __restrict__ gt) {
  const int b = blockIdx.y, mp0 = blockIdx.x * 64;
  const int c = threadIdx.x & 63, dm = threadIdx.x >> 6;
  const unsigned short* Y = yt + (size_t)b * HW_ * M3_;
  unsigned short* G = gt + (size_t)b * HWP_ * 64;
  for (int mm = dm; mm < 64; mm += 4) {
    const int mp = mp0 + mm;
    const int n00 = (mp >> 5) * 128 + (mp & 31) * 2;
    const float a0 = b2f(Y[(size_t)n00 * M3_ + 64 + c]);
    const float a1 = b2f(Y[(size_t)(n00 + 1) * M3_ + 64 + c]);
    const float a2 = b2f(Y[(size_t)(n00 + 64) * M3_ + 64 + c]);
    const float a3 = b2f(Y[(size_t)(n00 + 65) * M3_ + 64 + c]);
    G[(size_t)mp * 64 + c] = f2b(fmaxf(fmaxf(a0, a1), fmaxf(a2, a3)));
  }
}

// ---------------------------------------------------------------- K3b: vt[b][cv][mp] = maxpool(Yt cols 128..383)^T
__global__ __launch_bounds__(256) void k_pool_vt(const unsigned short* __restrict__ yt,
                                                 unsigned short* __restrict__ vt) {
  __shared__ unsigned short t[64][66];
  const int b = blockIdx.z, mp0 = blockIdx.x * 64, cv0 = blockIdx.y * 64;
  const unsigned short* Y = yt + (size_t)b * HW_ * M3_;
  const int c = threadIdx.x & 63, dm = threadIdx.x >> 6;
  for (int mm = dm; mm < 64; mm += 4) {
    const int mp = mp0 + mm;
    const int n00 = (mp >> 5) * 128 + (mp & 31) * 2;
    const float a0 = b2f(Y[(size_t)n00 * M3_ + 128 + cv0 + c]);
    const float a1 = b2f(Y[(size_t)(n00 + 1) * M3_ + 128 + cv0 + c]);
    const float a2 = b2f(Y[(size_t)(n00 + 64) * M3_ + 128 + cv0 + c]);
    const float a3 = b2f(Y[(size_t)(n00 + 65) * M3_ + 128 + cv0 + c]);
    t[mm][c] = f2b(fmaxf(fmaxf(a0, a1), fmaxf(a2, a3)));
  }
  __syncthreads();
  unsigned short* V = vt + (size_t)b * CV_ * HWP_;
  for (int cc = dm; cc < 64; cc += 4)
    V[(size_t)(cv0 + cc) * HWP_ + mp0 + c] = t[c][cc];
}

// ---------------------------------------------------------------- K4: flash attention, single-barrier dbuf pipeline
// KVBLK=32; K/V LDS double-buffered; per tile: {ds_write buf[nxt] | issue
// loads t+2 | compute buf[cur]} -> ONE barrier. Stage overlaps compute
// (T3-minimum, reg-staged, counted vmcnt via register deps). 4 waves x 32q.
__global__ __launch_bounds__(256, 2) void k_attn(
    const unsigned short* __restrict__ yt, const unsigned short* __restrict__ gt,
    const unsigned short* __restrict__ vt, unsigned short* __restrict__ oat) {
  __shared__ alignas(16) char smem[49152];
  // Ks dbuf 2x[32kv][64ch] (4KB each) @0; Vs dbuf 2x[256cv][32kv] (16KB each) @8192
  // Ps 4 waves x [32q][32kv] (2KB each) @40960; epilogue eps 64x264 bf16 @0
  const int lid = blockIdx.x;                              // 512 blocks
  const int swz = (lid & 7) * 64 + (lid >> 3);
  const int q0 = (swz & 31) * 128, b = swz >> 5;
  const int tid = threadIdx.x, lane = tid & 63, wid = tid >> 6;  // 4 waves
  const int q = lane & 15, g = lane >> 4;
  const unsigned short* Qg = yt + (size_t)b * HW_ * M3_ + (size_t)(q0 + wid * 32) * M3_;
  const unsigned short* Gg = gt + (size_t)b * HWP_ * 64;
  const unsigned short* Vg = vt + (size_t)b * CV_ * HWP_;
  unsigned short* P = (unsigned short*)(smem + 40960) + wid * 1024;  // 32q x 32kv
  // Q fragments: two 16-q groups, kept all kernel
  bf16x8 qf[2][2];
#pragma unroll
  for (int h = 0; h < 2; ++h)
#pragma unroll
    for (int kk = 0; kk < 2; ++kk)
      qf[h][kk] = *reinterpret_cast<const bf16x8*>(&Qg[(size_t)(h * 16 + q) * M3_ + kk * 32 + g * 8]);
  // staging helpers: K chunk r=tid>>3 (32 rows x 8 slots), V chunks r=i>>2 (256 rows x 4 slots)
  const int kr = tid >> 3, ks = tid & 7;
  f32x4 kreg, vreg[4];
  // prologue: tile 0 -> regs -> buf0; tile 1 -> regs
  kreg = *reinterpret_cast<const f32x4*>(&Gg[(size_t)kr * 64 + ks * 8]);
#pragma unroll
  for (int t = 0; t < 4; ++t) {
    const int i = tid + t * 256, r = i >> 2, s = i & 3;
    vreg[t] = *reinterpret_cast<const f32x4*>(&Vg[(size_t)r * HWP_ + s * 8]);
  }
  {
    unsigned short* Kb = (unsigned short*)smem;
    unsigned short* Vb = (unsigned short*)(smem + 8192);
    *reinterpret_cast<f32x4*>(&Kb[kr * 64 + (ks ^ (kr & 7)) * 8]) = kreg;
#pragma unroll
    for (int t = 0; t < 4; ++t) {
      const int i = tid + t * 256, r = i >> 2, s = i & 3;
      *reinterpret_cast<f32x4*>(&Vb[r * 32 + (s ^ (r & 3)) * 8]) = vreg[t];
    }
  }
  kreg = *reinterpret_cast<const f32x4*>(&Gg[(size_t)(32 + kr) * 64 + ks * 8]);
#pragma unroll
  for (int t = 0; t < 4; ++t) {
    const int i = tid + t * 256, r = i >> 2, s = i & 3;
    vreg[t] = *reinterpret_cast<const f32x4*>(&Vg[(size_t)r * HWP_ + 32 + s * 8]);
  }
  __syncthreads();
  f32x4 oacc[2][16] = {};
  float m_run[2] = {-1e30f, -1e30f}, l_run[2] = {0.f, 0.f};
  for (int it = 0; it < 32; ++it) {
    const int cur = it & 1;
    unsigned short* Kc = (unsigned short*)(smem + cur * 4096);
    unsigned short* Vc = (unsigned short*)(smem + 8192 + cur * 16384);
    // stage tile it+1 into the other buffer (overlaps compute below)
    if (it < 31) {
      unsigned short* Kn = (unsigned short*)(smem + (cur ^ 1) * 4096);
      unsigned short* Vn = (unsigned short*)(smem + 8192 + (cur ^ 1) * 16384);
      *reinterpret_cast<f32x4*>(&Kn[kr * 64 + (ks ^ (kr & 7)) * 8]) = kreg;
#pragma unroll
      for (int t = 0; t < 4; ++t) {
        const int i = tid + t * 256, r = i >> 2, s = i & 3;
        *reinterpret_cast<f32x4*>(&Vn[r * 32 + (s ^ (r & 3)) * 8]) = vreg[t];
      }
    }
    // issue loads for tile it+2
    if (it < 30) {
      const int kvn = (it + 2) * 32;
      kreg = *reinterpret_cast<const f32x4*>(&Gg[(size_t)(kvn + kr) * 64 + ks * 8]);
#pragma unroll
      for (int t = 0; t < 4; ++t) {
        const int i = tid + t * 256, r = i >> 2, s = i & 3;
        vreg[t] = *reinterpret_cast<const f32x4*>(&Vg[(size_t)r * HWP_ + kvn + s * 8]);
      }
    }
    // QK^T (swapped): kf shared across both q-groups; sacc rows kv(32), col q
    f32x4 sacc[2][2] = {};
#pragma unroll
    for (int kk = 0; kk < 2; ++kk) {
      bf16x8 kf[2];
#pragma unroll
      for (int i = 0; i < 2; ++i) {
        const int row = i * 16 + q;
        const int sl = (kk * 4 + g) ^ (row & 7);
        kf[i] = *reinterpret_cast<const bf16x8*>(&Kc[row * 64 + sl * 8]);
      }
#pragma unroll
      for (int h = 0; h < 2; ++h)
#pragma unroll
        for (int i = 0; i < 2; ++i) sacc[h][i] = mfma16(kf[i], qf[h][kk], sacc[h][i]);
    }
    // online softmax per q-group (log2 domain, defer-max)
#pragma unroll
    for (int h = 0; h < 2; ++h) {
      float tmax = -1e30f;
#pragma unroll
      for (int i = 0; i < 2; ++i)
#pragma unroll
        for (int r = 0; r < 4; ++r) tmax = fmaxf(tmax, sacc[h][i][r]);
      tmax = fmaxf(tmax, __shfl_xor(tmax, 16));
      tmax = fmaxf(tmax, __shfl_xor(tmax, 32));
      if (__any(tmax > m_run[h] + 11.0f)) {
        const float mnew = fmaxf(m_run[h], tmax);
        const float alpha = exp2f(m_run[h] - mnew);
        m_run[h] = mnew;
        l_run[h] *= alpha;
        float al[4];
#pragma unroll
        for (int r = 0; r < 4; ++r) al[r] = __shfl(alpha, g * 4 + r);
#pragma unroll
        for (int j = 0; j < 16; ++j) {
          oacc[h][j][0] *= al[0]; oacc[h][j][1] *= al[1];
          oacc[h][j][2] *= al[2]; oacc[h][j][3] *= al[3];
        }
      }
      const int qg = h * 16 + q;
      float lsum = 0.f;
#pragma unroll
      for (int i = 0; i < 2; ++i) {
        const float p0 = exp2f(sacc[h][i][0] - m_run[h]);
        const float p1 = exp2f(sacc[h][i][1] - m_run[h]);
        const float p2 = exp2f(sacc[h][i][2] - m_run[h]);
        const float p3 = exp2f(sacc[h][i][3] - m_run[h]);
        lsum += (p0 + p1) + (p2 + p3);
        u32x2 pw;
        pw[0] = ((unsigned)f2b(p1) << 16) | f2b(p0);
        pw[1] = ((unsigned)f2b(p3) << 16) | f2b(p2);
        // kv = 16i + 4g + r -> 8B at byte kv*2; chunk c = 2i + (g>>1), off (g&1)*8
        const int c = 2 * i + (g >> 1);
        *reinterpret_cast<u32x2*>(&P[qg * 32 + ((c ^ (qg & 3)) * 8) + (g & 1) * 4]) = pw;
      }
      lsum += __shfl_xor(lsum, 16);
      lsum += __shfl_xor(lsum, 32);
      l_run[h] += lsum;
    }
    // PV: pa per group (k-slice g*8); each vf read feeds both groups
    __builtin_amdgcn_s_setprio(1);
    bf16x8 pa[2];
#pragma unroll
    for (int h = 0; h < 2; ++h) {
      const int qg = h * 16 + q;
      pa[h] = *reinterpret_cast<const bf16x8*>(&P[qg * 32 + ((g ^ (qg & 3)) * 8)]);
    }
#pragma unroll
    for (int j = 0; j < 16; ++j) {
      const int row = j * 16 + q;
      const int sl = g ^ (row & 3);
      const bf16x8 vf = *reinterpret_cast<const bf16x8*>(&Vc[row * 32 + sl * 8]);
      oacc[0][j] = mfma16(pa[0], vf, oacc[0][j]);
      oacc[1][j] = mfma16(pa[1], vf, oacc[1][j]);
    }
    __builtin_amdgcn_s_setprio(0);
    __syncthreads();   // single barrier per tile: buf[nxt] ready, buf[cur] free
  }
  // epilogue: normalize, repack 2 chunks of 64 rows, dwordx4 store
  float linv[2][4];
#pragma unroll
  for (int h = 0; h < 2; ++h) {
    const float myinv = 1.f / l_run[h];
#pragma unroll
    for (int r = 0; r < 4; ++r) linv[h][r] = __shfl(myinv, g * 4 + r);
  }
  unsigned short* eps = (unsigned short*)smem;   // 64 x 264 bf16 = 33792B
  unsigned short* O = oat + (size_t)b * HW_ * CV_ + (size_t)q0 * CV_;
#pragma unroll
  for (int ch = 0; ch < 2; ++ch) {
    __syncthreads();
    if ((wid >> 1) == ch) {
#pragma unroll
      for (int h = 0; h < 2; ++h)
#pragma unroll
        for (int j = 0; j < 16; ++j)
#pragma unroll
          for (int r = 0; r < 4; ++r) {
            const int row = (wid & 1) * 32 + h * 16 + g * 4 + r;
            const int cv = j * 16 + q;
            eps[row * 264 + cv] = f2b(oacc[h][j][r] * linv[h][r]);
          }
    }
    __syncthreads();
#pragma unroll
    for (int t = 0; t < 8; ++t) {
      const int row = t * 8 + (tid >> 5);
      const int cv8 = (tid & 31) * 8;
      *reinterpret_cast<f32x4*>(&O[(size_t)(ch * 64 + row) * CV_ + cv8]) =
          *reinterpret_cast<const f32x4*>(&eps[row * 264 + cv8]);
    }
  }
}

// ---------------------------------------------------------------- K5: out[b][co][n] = gamma * wo@Oatt^T + x
__global__ __launch_bounds__(256) void k_gemm_out(
    const unsigned short* __restrict__ oat, const unsigned short* __restrict__ wob,
    const float* __restrict__ x, const float* __restrict__ gamma,
    float* __restrict__ out) {
  __shared__ alignas(16) char smem[32768];
  unsigned short* As = (unsigned short*)smem;
  unsigned short* Bs = (unsigned short*)(smem + 16384);
  const int lid = blockIdx.x;
  const int swz = (lid & 7) * 256 + (lid >> 3);
  const int ct = swz & 3, nt = (swz >> 2) & 31, b = swz >> 7;
  const int n0 = nt * 128, co0 = ct * 128;
  const unsigned short* Ap = wob + (size_t)co0 * CV_;
  const unsigned short* Bp = oat + (size_t)b * HW_ * CV_ + (size_t)n0 * CV_;
  const int tid = threadIdx.x, lane = tid & 63, wid = tid >> 6;
  const int wc = (wid >> 1) * 64, wn = (wid & 1) * 64;
  f32x4 acc[4][4] = {};
  for (int k0 = 0; k0 < CV_; k0 += 64) {
    __syncthreads();
#pragma unroll
    for (int i = 0; i < 4; ++i) {
      const int r = i * 32 + (tid >> 3);
      const int s = tid & 7, ss = s ^ (r & 7);
      *reinterpret_cast<f32x4*>(&As[r * 64 + ss * 8]) =
          *reinterpret_cast<const f32x4*>(&Ap[(size_t)r * CV_ + k0 + s * 8]);
      *reinterpret_cast<f32x4*>(&Bs[r * 64 + ss * 8]) =
          *reinterpret_cast<const f32x4*>(&Bp[(size_t)r * CV_ + k0 + s * 8]);
    }
    __syncthreads();
#pragma unroll
    for (int kk = 0; kk < 2; ++kk) {
      bf16x8 af[4], bfr[4];
#pragma unroll
      for (int i = 0; i < 4; ++i) {
        const int r = wc + i * 16 + (lane & 15);
        const int slot = (kk * 4 + (lane >> 4)) ^ (r & 7);
        af[i] = *reinterpret_cast<const bf16x8*>(&As[r * 64 + slot * 8]);
      }
#pragma unroll
      for (int j = 0; j < 4; ++j) {
        const int r = wn + j * 16 + (lane & 15);
        const int slot = (kk * 4 + (lane >> 4)) ^ (r & 7);
        bfr[j] = *reinterpret_cast<const bf16x8*>(&Bs[r * 64 + slot * 8]);
      }
#pragma unroll
      for (int i = 0; i < 4; ++i)
#pragma unroll
        for (int j = 0; j < 4; ++j) acc[i][j] = mfma16(af[i], bfr[j], acc[i][j]);
    }
  }
  float* eps = (float*)smem;
  const float g = gamma[0];
  const size_t base = (size_t)b * C_ * HW_;
#pragma unroll
  for (int h = 0; h < 4; ++h) {
    __syncthreads();
    if ((wid >> 1) == (h >> 1)) {
#pragma unroll
      for (int ii = 0; ii < 2; ++ii) {
        const int i = (h & 1) * 2 + ii;
#pragma unroll
        for (int j = 0; j < 4; ++j)
#pragma unroll
          for (int r = 0; r < 4; ++r) {
            const int col2 = ii * 16 + (lane >> 4) * 4 + r;
            const int nl = wn + j * 16 + (lane & 15);
            eps[col2 * 132 + nl] = acc[i][j][r];
          }
      }
    }
    __syncthreads();
#pragma unroll
    for (int t = 0; t < 4; ++t) {
      const int row = t * 8 + (tid >> 5);
      const int col = (tid & 31) * 4;
      const size_t goff = base + (size_t)(co0 + h * 32 + row) * HW_ + n0 + col;
      const f32x4 xv = *reinterpret_cast<const f32x4*>(&x[goff]);
      const f32x4 av = *reinterpret_cast<const f32x4*>(&eps[row * 132 + col]);
      f32x4 ov;
      ov[0] = g * av[0] + xv[0];
      ov[1] = g * av[1] + xv[1];
      ov[2] = g * av[2] + xv[2];
      ov[3] = g * av[3] + xv[3];
      *reinterpret_cast<f32x4*>(&out[goff]) = ov;
    }
  }
}

// ---------------------------------------------------------------- launcher
extern "C" void kernel_launch(void* const* d_in, const int* in_sizes, int n_in,
                              void* d_out, int out_size, void* d_ws, size_t ws_size,
                              hipStream_t stream) {
  (void)in_sizes; (void)n_in; (void)out_size; (void)ws_size;
  const float* x     = (const float*)d_in[0];
  const float* Wq    = (const float*)d_in[1];
  const float* Wk    = (const float*)d_in[2];
  const float* Wv    = (const float*)d_in[3];
  const float* Wo    = (const float*)d_in[4];
  const float* gamma = (const float*)d_in[5];
  float* out = (float*)d_out;
  char* ws = (char*)d_ws;

  unsigned short* wqkv = (unsigned short*)(ws);                 // 384*512*2
  unsigned short* wob  = (unsigned short*)(ws + 393216);        // 512*256*2
  unsigned short* xb   = (unsigned short*)(ws + 655360);        // 64MB
  unsigned short* yt   = (unsigned short*)(ws + 67764224);      // 48MB
  unsigned short* gt   = (unsigned short*)(ws + 118095872);     // 2MB
  unsigned short* vt   = (unsigned short*)(ws + 120193024);     // 8MB
  unsigned short* oat  = xb;   // alias: xb dead after k_gemm_qkv
  float* wt = (float*)yt;      // alias: wT only live during specnorm (yt written later)

  k_transpose<<<dim3(64, 8, 16), 256, 0, stream>>>(x, xb);
  k_wtrans<<<dim3(8, 8, 4), 256, 0, stream>>>(Wq, Wk, Wv, Wo, wt);
  k_specnorm<<<4, 1024, 0, stream>>>(Wq, Wk, Wv, Wo, wt, wqkv, wob);
  k_gemm_qkv<<<1536, 256, 0, stream>>>(xb, wqkv, yt);
  k_pool_g<<<dim3(16, 16), 256, 0, stream>>>(yt, gt);
  k_pool_vt<<<dim3(16, 4, 16), 256, 0, stream>>>(yt, vt);
  k_attn<<<512, 256, 0, stream>>>(yt, gt, vt, oat);
  k_gemm_out<<<2048, 256, 0, stream>>>(oat, wob, x, gamma, out);
}

// Round 12
// 292.209 us; speedup vs baseline: 1.6316x; 1.0139x over previous
//
#include <hip/hip_runtime.h>
#include <cstdint>

typedef __attribute__((ext_vector_type(8))) short bf16x8;
typedef __attribute__((ext_vector_type(4))) float f32x4;
typedef __attribute__((ext_vector_type(2))) unsigned int u32x2;

#define B_   16
#define C_   512
#define HW_  4096
#define M3_  384
#define HWP_ 1024
#define CV_  256

__device__ __forceinline__ unsigned short f2b(float f) {
  union { float f; unsigned u; } v; v.f = f;
  unsigned r = v.u + 0x7fffu + ((v.u >> 16) & 1u);   // RNE
  return (unsigned short)(r >> 16);
}
__device__ __forceinline__ float b2f(unsigned short b) {
  union { unsigned u; float f; } v; v.u = ((unsigned)b) << 16;
  return v.f;
}
__device__ __forceinline__ f32x4 mfma16(bf16x8 a, bf16x8 b, f32x4 c) {
  return __builtin_amdgcn_mfma_f32_16x16x32_bf16(a, b, c, 0, 0, 0);
}
// async global->LDS, 16B per lane; LDS dest = wave-uniform base + lane*16
__device__ __forceinline__ void gload_lds16(const unsigned short* g, unsigned short* l) {
  __builtin_amdgcn_global_load_lds(
      (const __attribute__((address_space(1))) void*)g,
      (__attribute__((address_space(3))) void*)l, 16, 0, 0);
}

// ---------------------------------------------------------------- K0: x [b][c][n] f32 -> xb [b][n][c] bf16
__global__ __launch_bounds__(256) void k_transpose(const float* __restrict__ x,
                                                   unsigned short* __restrict__ xb) {
  __shared__ unsigned short t[64][66];
  const int b = blockIdx.z, k0 = blockIdx.y * 64, n0 = blockIdx.x * 64;
  const float* xp = x + (size_t)b * C_ * HW_;
  const int ln = threadIdx.x & 63, g = threadIdx.x >> 6;
  for (int kk = g; kk < 64; kk += 4)
    t[kk][ln] = f2b(xp[(size_t)(k0 + kk) * HW_ + n0 + ln]);
  __syncthreads();
  unsigned short* xo = xb + (size_t)b * HW_ * C_;
  for (int nn = g; nn < 64; nn += 4)
    xo[(size_t)(n0 + nn) * C_ + k0 + ln] = t[ln][nn];
}

// ---------------------------------------------------------------- K0b: transpose the 4 weight matrices (f32)
__global__ __launch_bounds__(256) void k_wtrans(
    const float* __restrict__ Wq, const float* __restrict__ Wk,
    const float* __restrict__ Wv, const float* __restrict__ Wo,
    float* __restrict__ wt) {
  const float* w; int out, in; float* dst;
  switch (blockIdx.z) {
    case 0: w = Wq; out = 64;  in = 512; dst = wt;          break;
    case 1: w = Wk; out = 64;  in = 512; dst = wt + 32768;  break;
    case 2: w = Wv; out = 256; in = 512; dst = wt + 65536;  break;
    default: w = Wo; out = 512; in = 256; dst = wt + 196608; break;
  }
  const int o0 = blockIdx.y * 64, i0 = blockIdx.x * 64;
  if (o0 >= out || i0 >= in) return;
  __shared__ float t[64][65];
  const int ln = threadIdx.x & 63, g = threadIdx.x >> 6;
  for (int oo = g; oo < 64; oo += 4)
    t[oo][ln] = w[(size_t)(o0 + oo) * in + i0 + ln];
  __syncthreads();
  for (int ii = g; ii < 64; ii += 4)
    dst[(size_t)(i0 + ii) * out + o0 + ln] = t[ln][ii];
}

// ---------------------------------------------------------------- K1: spectral norm, 1024 thr / matrix
__device__ __forceinline__ float breduce1024(float val, float* red) {
  __syncthreads();
#pragma unroll
  for (int off = 32; off > 0; off >>= 1) val += __shfl_down(val, off);
  if ((threadIdx.x & 63) == 0) red[threadIdx.x >> 6] = val;
  __syncthreads();
  float s = 0.f;
#pragma unroll
  for (int i = 0; i < 16; ++i) s += red[i];
  return s;
}

__global__ __launch_bounds__(1024) void k_specnorm(
    const float* __restrict__ Wq, const float* __restrict__ Wk,
    const float* __restrict__ Wv, const float* __restrict__ Wo,
    const float* __restrict__ wt,
    unsigned short* __restrict__ wqkv, unsigned short* __restrict__ wob) {
  __shared__ float u[512], v[512];
  __shared__ float part[4096];
  __shared__ float red[16];
  const float* w; const float* wT; int out, in; unsigned short* dst;
  switch (blockIdx.x) {
    case 0: w = Wq; wT = wt;          out = 64;  in = 512; dst = wqkv;             break;
    case 1: w = Wk; wT = wt + 32768;  out = 64;  in = 512; dst = wqkv + 64 * 512;  break;
    case 2: w = Wv; wT = wt + 65536;  out = 256; in = 512; dst = wqkv + 128 * 512; break;
    default: w = Wo; wT = wt + 196608; out = 512; in = 256; dst = wob;             break;
  }
  const int tid = threadIdx.x;
  const float rs = rsqrtf((float)out);
  if (tid < out) u[tid] = rs;
  __syncthreads();
  for (int it = 0; it < 5; ++it) {
    {
      const int G = in >> 2, nch = 1024 / G;
      const int ch = tid / G, grp = tid - ch * G;
      const int rpc = out / nch, obase = ch * rpc;
      f32x4 acc = {0.f, 0.f, 0.f, 0.f};
#pragma unroll 8
      for (int r = 0; r < rpc; ++r) {
        const int o = obase + r;
        const f32x4 wv = *reinterpret_cast<const f32x4*>(&w[(size_t)o * in + grp * 4]);
        const float uo = u[o];
        acc[0] += wv[0] * uo; acc[1] += wv[1] * uo;
        acc[2] += wv[2] * uo; acc[3] += wv[3] * uo;
      }
      *reinterpret_cast<f32x4*>(&part[ch * in + grp * 4]) = acc;
      __syncthreads();
      if (tid < in) {
        float s = 0.f;
        for (int c2 = 0; c2 < nch; ++c2) s += part[c2 * in + tid];
        v[tid] = s;
      }
    }
    {
      float ss = 0.f;
      __syncthreads();
      if (tid < in) ss = v[tid] * v[tid];
      ss = breduce1024(ss, red);
      const float sv = 1.f / (sqrtf(ss) + 1e-12f);
      if (tid < in) v[tid] *= sv;
      __syncthreads();
    }
    {
      const int G = out >> 2, nch = 1024 / G;
      const int ch = tid / G, grp = tid - ch * G;
      const int cpc = in / nch, cbase = ch * cpc;
      f32x4 acc = {0.f, 0.f, 0.f, 0.f};
#pragma unroll 8
      for (int r = 0; r < cpc; ++r) {
        const int c = cbase + r;
        const f32x4 wv = *reinterpret_cast<const f32x4*>(&wT[(size_t)c * out + grp * 4]);
        const float vc = v[c];
        acc[0] += wv[0] * vc; acc[1] += wv[1] * vc;
        acc[2] += wv[2] * vc; acc[3] += wv[3] * vc;
      }
      *reinterpret_cast<f32x4*>(&part[ch * out + grp * 4]) = acc;
      __syncthreads();
      if (tid < out) {
        float s = 0.f;
        for (int c2 = 0; c2 < nch; ++c2) s += part[c2 * out + tid];
        u[tid] = s;
      }
    }
    {
      float su = 0.f;
      __syncthreads();
      if (tid < out) su = u[tid] * u[tid];
      su = breduce1024(su, red);
      const float sv2 = 1.f / (sqrtf(su) + 1e-12f);
      if (tid < out) u[tid] *= sv2;
      __syncthreads();
    }
  }
  float sp = 0.f;
  {
    const int G = out >> 2, nch = 1024 / G;
    const int ch = tid / G, grp = tid - ch * G;
    const int cpc = in / nch, cbase = ch * cpc;
    f32x4 acc = {0.f, 0.f, 0.f, 0.f};
#pragma unroll 8
    for (int r = 0; r < cpc; ++r) {
      const int c = cbase + r;
      const f32x4 wv = *reinterpret_cast<const f32x4*>(&wT[(size_t)c * out + grp * 4]);
      const float vc = v[c];
      acc[0] += wv[0] * vc; acc[1] += wv[1] * vc;
      acc[2] += wv[2] * vc; acc[3] += wv[3] * vc;
    }
    *reinterpret_cast<f32x4*>(&part[ch * out + grp * 4]) = acc;
    __syncthreads();
    if (tid < out) {
      float s = 0.f;
      for (int c2 = 0; c2 < nch; ++c2) s += part[c2 * out + tid];
      sp = s * u[tid];
    }
  }
  sp = breduce1024(sp, red);
  const float oscale = (blockIdx.x == 0) ? 1.44269504f : 1.0f;
  const float inv_sigma = (1.f / sp) * oscale;
  const int total = out * in;
  for (int i = tid * 4; i < total; i += 4096) {
    const f32x4 wv = *reinterpret_cast<const f32x4*>(&w[i]);
    u32x2 pw;
    pw[0] = ((unsigned)f2b(wv[1] * inv_sigma) << 16) | f2b(wv[0] * inv_sigma);
    pw[1] = ((unsigned)f2b(wv[3] * inv_sigma) << 16) | f2b(wv[2] * inv_sigma);
    *reinterpret_cast<u32x2*>(&dst[i]) = pw;
  }
}

// ---------------------------------------------------------------- K2: Yt[b][n][m] = xb[b][n][k] * wqkv[m][k]
// Staging via global_load_lds (linear LDS dest, pre-swizzled global source).
__global__ __launch_bounds__(256) void k_gemm_qkv(
    const unsigned short* __restrict__ xb, const unsigned short* __restrict__ wqkv,
    unsigned short* __restrict__ yt) {
  __shared__ alignas(16) char smem[32768];
  unsigned short* As = (unsigned short*)smem;
  unsigned short* Bs = (unsigned short*)(smem + 16384);
  const int lid = blockIdx.x;
  const int swz = (lid & 7) * 192 + (lid >> 3);
  const int mt = swz % 3, rest = swz / 3;
  const int nt = rest & 31, b = rest >> 5;
  const int n0 = nt * 128, m0 = mt * 128;
  const unsigned short* Ap = xb + (size_t)b * HW_ * C_ + (size_t)n0 * C_;
  const unsigned short* Bp = wqkv + (size_t)m0 * C_;
  const int tid = threadIdx.x, lane = tid & 63, wid = tid >> 6;
  const int wn = (wid >> 1) * 64, wm = (wid & 1) * 64;
  f32x4 acc[4][4] = {};
  for (int k0 = 0; k0 < C_; k0 += 64) {
    __syncthreads();
#pragma unroll
    for (int i = 0; i < 4; ++i) {
      const int r = i * 32 + (tid >> 3);           // per-lane row
      const int s = tid & 7;                       // per-lane 16B slot
      const int rw = i * 32 + wid * 8;             // wave-uniform base row
      const size_t goff = (size_t)r * C_ + k0 + (size_t)((s ^ (r & 7)) * 8);
      gload_lds16(&Ap[goff], &As[rw * 64]);
      gload_lds16(&Bp[goff], &Bs[rw * 64]);
    }
    __syncthreads();
#pragma unroll
    for (int kk = 0; kk < 2; ++kk) {
      bf16x8 af[4], bfr[4];
#pragma unroll
      for (int i = 0; i < 4; ++i) {
        const int r = wn + i * 16 + (lane & 15);
        const int slot = (kk * 4 + (lane >> 4)) ^ (r & 7);
        af[i] = *reinterpret_cast<const bf16x8*>(&As[r * 64 + slot * 8]);
      }
#pragma unroll
      for (int j = 0; j < 4; ++j) {
        const int r = wm + j * 16 + (lane & 15);
        const int slot = (kk * 4 + (lane >> 4)) ^ (r & 7);
        bfr[j] = *reinterpret_cast<const bf16x8*>(&Bs[r * 64 + slot * 8]);
      }
#pragma unroll
      for (int i = 0; i < 4; ++i)
#pragma unroll
        for (int j = 0; j < 4; ++j) acc[i][j] = mfma16(af[i], bfr[j], acc[i][j]);
    }
  }
  unsigned short* eps = (unsigned short*)smem;
  unsigned short* Y = yt + (size_t)b * HW_ * M3_;
#pragma unroll
  for (int h = 0; h < 2; ++h) {
    __syncthreads();
    if ((wid >> 1) == h) {
#pragma unroll
      for (int i = 0; i < 4; ++i)
#pragma unroll
        for (int j = 0; j < 4; ++j)
#pragma unroll
          for (int r = 0; r < 4; ++r) {
            const int nl = i * 16 + (lane >> 4) * 4 + r;
            const int ml = wm + j * 16 + (lane & 15);
            eps[nl * 136 + ml] = f2b(acc[i][j][r]);
          }
    }
    __syncthreads();
#pragma unroll
    for (int t = 0; t < 4; ++t) {
      const int row = t * 16 + (tid >> 4);
      const int m8 = (tid & 15) * 8;
      *reinterpret_cast<f32x4*>(&Y[(size_t)(n0 + h * 64 + row) * M3_ + m0 + m8]) =
          *reinterpret_cast<const f32x4*>(&eps[row * 136 + m8]);
    }
  }
}

// ---------------------------------------------------------------- K3a: gt[b][mp][c] = maxpool(Yt cols 64..127)
__global__ __launch_bounds__(256) void k_pool_g(const unsigned short* __restrict__ yt,
                                                unsigned short* __restrict__ gt) {
  const int b = blockIdx.y, mp0 = blockIdx.x * 64;
  const int c = threadIdx.x & 63, dm = threadIdx.x >> 6;
  const unsigned short* Y = yt + (size_t)b * HW_ * M3_;
  unsigned short* G = gt + (size_t)b * HWP_ * 64;
  for (int mm = dm; mm < 64; mm += 4) {
    const int mp = mp0 + mm;
    const int n00 = (mp >> 5) * 128 + (mp & 31) * 2;
    const float a0 = b2f(Y[(size_t)n00 * M3_ + 64 + c]);
    const float a1 = b2f(Y[(size_t)(n00 + 1) * M3_ + 64 + c]);
    const float a2 = b2f(Y[(size_t)(n00 + 64) * M3_ + 64 + c]);
    const float a3 = b2f(Y[(size_t)(n00 + 65) * M3_ + 64 + c]);
    G[(size_t)mp * 64 + c] = f2b(fmaxf(fmaxf(a0, a1), fmaxf(a2, a3)));
  }
}

// ---------------------------------------------------------------- K3b: vt[b][cv][mp] = maxpool(Yt cols 128..383)^T
__global__ __launch_bounds__(256) void k_pool_vt(const unsigned short* __restrict__ yt,
                                                 unsigned short* __restrict__ vt) {
  __shared__ unsigned short t[64][66];
  const int b = blockIdx.z, mp0 = blockIdx.x * 64, cv0 = blockIdx.y * 64;
  const unsigned short* Y = yt + (size_t)b * HW_ * M3_;
  const int c = threadIdx.x & 63, dm = threadIdx.x >> 6;
  for (int mm = dm; mm < 64; mm += 4) {
    const int mp = mp0 + mm;
    const int n00 = (mp >> 5) * 128 + (mp & 31) * 2;
    const float a0 = b2f(Y[(size_t)n00 * M3_ + 128 + cv0 + c]);
    const float a1 = b2f(Y[(size_t)(n00 + 1) * M3_ + 128 + cv0 + c]);
    const float a2 = b2f(Y[(size_t)(n00 + 64) * M3_ + 128 + cv0 + c]);
    const float a3 = b2f(Y[(size_t)(n00 + 65) * M3_ + 128 + cv0 + c]);
    t[mm][c] = f2b(fmaxf(fmaxf(a0, a1), fmaxf(a2, a3)));
  }
  __syncthreads();
  unsigned short* V = vt + (size_t)b * CV_ * HWP_;
  for (int cc = dm; cc < 64; cc += 4)
    V[(size_t)(cv0 + cc) * HWP_ + mp0 + c] = t[c][cc];
}

// ---------------------------------------------------------------- K4: flash attention, single-barrier dbuf pipeline
// KVBLK=32; V/P rows padded to 80B (5x16B): conflict-free without XOR.
// Per tile: {ds_write buf[nxt] | issue loads t+2 | compute buf[cur]} -> 1 barrier.
__global__ __launch_bounds__(256, 2) void k_attn(
    const unsigned short* __restrict__ yt, const unsigned short* __restrict__ gt,
    const unsigned short* __restrict__ vt, unsigned short* __restrict__ oat) {
  __shared__ alignas(16) char smem[59392];
  // Ks dbuf 2x[32kv][64ch] 4KB @0; Vs dbuf 2x[256cv][40sh] 20KB @8192
  // Ps 4 waves x [32q][40sh] 2.5KB @49152; epilogue eps 64x264 bf16 @0
  const int lid = blockIdx.x;                              // 512 blocks
  const int swz = (lid & 7) * 64 + (lid >> 3);
  const int q0 = (swz & 31) * 128, b = swz >> 5;
  const int tid = threadIdx.x, lane = tid & 63, wid = tid >> 6;  // 4 waves
  const int q = lane & 15, g = lane >> 4;
  const unsigned short* Qg = yt + (size_t)b * HW_ * M3_ + (size_t)(q0 + wid * 32) * M3_;
  const unsigned short* Gg = gt + (size_t)b * HWP_ * 64;
  const unsigned short* Vg = vt + (size_t)b * CV_ * HWP_;
  unsigned short* P = (unsigned short*)(smem + 49152) + wid * 1280;  // 32q x 40sh
  // Q fragments: two 16-q groups, kept all kernel
  bf16x8 qf[2][2];
#pragma unroll
  for (int h = 0; h < 2; ++h)
#pragma unroll
    for (int kk = 0; kk < 2; ++kk)
      qf[h][kk] = *reinterpret_cast<const bf16x8*>(&Qg[(size_t)(h * 16 + q) * M3_ + kk * 32 + g * 8]);
  const int kr = tid >> 3, ks = tid & 7;
  f32x4 kreg, vreg[4];
  // prologue: tile 0 -> regs -> buf0; tile 1 -> regs
  kreg = *reinterpret_cast<const f32x4*>(&Gg[(size_t)kr * 64 + ks * 8]);
#pragma unroll
  for (int t = 0; t < 4; ++t) {
    const int i = tid + t * 256, r = i >> 2, s = i & 3;
    vreg[t] = *reinterpret_cast<const f32x4*>(&Vg[(size_t)r * HWP_ + s * 8]);
  }
  {
    unsigned short* Kb = (unsigned short*)smem;
    unsigned short* Vb = (unsigned short*)(smem + 8192);
    *reinterpret_cast<f32x4*>(&Kb[kr * 64 + (ks ^ (kr & 7)) * 8]) = kreg;
#pragma unroll
    for (int t = 0; t < 4; ++t) {
      const int i = tid + t * 256, r = i >> 2, s = i & 3;
      *reinterpret_cast<f32x4*>(&Vb[r * 40 + s * 8]) = vreg[t];
    }
  }
  kreg = *reinterpret_cast<const f32x4*>(&Gg[(size_t)(32 + kr) * 64 + ks * 8]);
#pragma unroll
  for (int t = 0; t < 4; ++t) {
    const int i = tid + t * 256, r = i >> 2, s = i & 3;
    vreg[t] = *reinterpret_cast<const f32x4*>(&Vg[(size_t)r * HWP_ + 32 + s * 8]);
  }
  __syncthreads();
  f32x4 oacc[2][16] = {};
  float m_run[2] = {-1e30f, -1e30f}, l_run[2] = {0.f, 0.f};
  for (int it = 0; it < 32; ++it) {
    const int cur = it & 1;
    unsigned short* Kc = (unsigned short*)(smem + cur * 4096);
    unsigned short* Vc = (unsigned short*)(smem + 8192 + cur * 20480);
    // stage tile it+1 into the other buffer (overlaps compute below)
    if (it < 31) {
      unsigned short* Kn = (unsigned short*)(smem + (cur ^ 1) * 4096);
      unsigned short* Vn = (unsigned short*)(smem + 8192 + (cur ^ 1) * 20480);
      *reinterpret_cast<f32x4*>(&Kn[kr * 64 + (ks ^ (kr & 7)) * 8]) = kreg;
#pragma unroll
      for (int t = 0; t < 4; ++t) {
        const int i = tid + t * 256, r = i >> 2, s = i & 3;
        *reinterpret_cast<f32x4*>(&Vn[r * 40 + s * 8]) = vreg[t];
      }
    }
    // issue loads for tile it+2
    if (it < 30) {
      const int kvn = (it + 2) * 32;
      kreg = *reinterpret_cast<const f32x4*>(&Gg[(size_t)(kvn + kr) * 64 + ks * 8]);
#pragma unroll
      for (int t = 0; t < 4; ++t) {
        const int i = tid + t * 256, r = i >> 2, s = i & 3;
        vreg[t] = *reinterpret_cast<const f32x4*>(&Vg[(size_t)r * HWP_ + kvn + s * 8]);
      }
    }
    // QK^T (swapped): kf shared across both q-groups; sacc rows kv(32), col q
    f32x4 sacc[2][2] = {};
#pragma unroll
    for (int kk = 0; kk < 2; ++kk) {
      bf16x8 kf[2];
#pragma unroll
      for (int i = 0; i < 2; ++i) {
        const int row = i * 16 + q;
        const int sl = (kk * 4 + g) ^ (row & 7);
        kf[i] = *reinterpret_cast<const bf16x8*>(&Kc[row * 64 + sl * 8]);
      }
#pragma unroll
      for (int h = 0; h < 2; ++h)
#pragma unroll
        for (int i = 0; i < 2; ++i) sacc[h][i] = mfma16(kf[i], qf[h][kk], sacc[h][i]);
    }
    // online softmax per q-group (log2 domain, defer-max)
#pragma unroll
    for (int h = 0; h < 2; ++h) {
      float tmax = -1e30f;
#pragma unroll
      for (int i = 0; i < 2; ++i)
#pragma unroll
        for (int r = 0; r < 4; ++r) tmax = fmaxf(tmax, sacc[h][i][r]);
      tmax = fmaxf(tmax, __shfl_xor(tmax, 16));
      tmax = fmaxf(tmax, __shfl_xor(tmax, 32));
      if (__any(tmax > m_run[h] + 11.0f)) {
        const float mnew = fmaxf(m_run[h], tmax);
        const float alpha = exp2f(m_run[h] - mnew);
        m_run[h] = mnew;
        l_run[h] *= alpha;
        float al[4];
#pragma unroll
        for (int r = 0; r < 4; ++r) al[r] = __shfl(alpha, g * 4 + r);
#pragma unroll
        for (int j = 0; j < 16; ++j) {
          oacc[h][j][0] *= al[0]; oacc[h][j][1] *= al[1];
          oacc[h][j][2] *= al[2]; oacc[h][j][3] *= al[3];
        }
      }
      const int qg = h * 16 + q;
      float lsum = 0.f;
#pragma unroll
      for (int i = 0; i < 2; ++i) {
        const float p0 = exp2f(sacc[h][i][0] - m_run[h]);
        const float p1 = exp2f(sacc[h][i][1] - m_run[h]);
        const float p2 = exp2f(sacc[h][i][2] - m_run[h]);
        const float p3 = exp2f(sacc[h][i][3] - m_run[h]);
        lsum += (p0 + p1) + (p2 + p3);
        u32x2 pw;
        pw[0] = ((unsigned)f2b(p1) << 16) | f2b(p0);
        pw[1] = ((unsigned)f2b(p3) << 16) | f2b(p2);
        const int c = 2 * i + (g >> 1);   // kv 16B-chunk
        *reinterpret_cast<u32x2*>(&P[qg * 40 + c * 8 + (g & 1) * 4]) = pw;
      }
      lsum += __shfl_xor(lsum, 16);
      lsum += __shfl_xor(lsum, 32);
      l_run[h] += lsum;
    }
    // PV: pa per group (k-slice g); each vf read feeds both groups
    __builtin_amdgcn_s_setprio(1);
    bf16x8 pa[2];
#pragma unroll
    for (int h = 0; h < 2; ++h) {
      const int qg = h * 16 + q;
      pa[h] = *reinterpret_cast<const bf16x8*>(&P[qg * 40 + g * 8]);
    }
#pragma unroll
    for (int j = 0; j < 16; ++j) {
      const int row = j * 16 + q;
      const bf16x8 vf = *reinterpret_cast<const bf16x8*>(&Vc[row * 40 + g * 8]);
      oacc[0][j] = mfma16(pa[0], vf, oacc[0][j]);
      oacc[1][j] = mfma16(pa[1], vf, oacc[1][j]);
    }
    __builtin_amdgcn_s_setprio(0);
    __syncthreads();   // single barrier per tile: buf[nxt] ready, buf[cur] free
  }
  // epilogue: normalize, repack 2 chunks of 64 rows, dwordx4 store
  float linv[2][4];
#pragma unroll
  for (int h = 0; h < 2; ++h) {
    const float myinv = 1.f / l_run[h];
#pragma unroll
    for (int r = 0; r < 4; ++r) linv[h][r] = __shfl(myinv, g * 4 + r);
  }
  unsigned short* eps = (unsigned short*)smem;   // 64 x 264 bf16 = 33792B
  unsigned short* O = oat + (size_t)b * HW_ * CV_ + (size_t)q0 * CV_;
#pragma unroll
  for (int ch = 0; ch < 2; ++ch) {
    __syncthreads();
    if ((wid >> 1) == ch) {
#pragma unroll
      for (int h = 0; h < 2; ++h)
#pragma unroll
        for (int j = 0; j < 16; ++j)
#pragma unroll
          for (int r = 0; r < 4; ++r) {
            const int row = (wid & 1) * 32 + h * 16 + g * 4 + r;
            const int cv = j * 16 + q;
            eps[row * 264 + cv] = f2b(oacc[h][j][r] * linv[h][r]);
          }
    }
    __syncthreads();
#pragma unroll
    for (int t = 0; t < 8; ++t) {
      const int row = t * 8 + (tid >> 5);
      const int cv8 = (tid & 31) * 8;
      *reinterpret_cast<f32x4*>(&O[(size_t)(ch * 64 + row) * CV_ + cv8]) =
          *reinterpret_cast<const f32x4*>(&eps[row * 264 + cv8]);
    }
  }
}

// ---------------------------------------------------------------- K5: out[b][co][n] = gamma * wo@Oatt^T + x
// Staging via global_load_lds (linear LDS dest, pre-swizzled global source).
__global__ __launch_bounds__(256) void k_gemm_out(
    const unsigned short* __restrict__ oat, const unsigned short* __restrict__ wob,
    const float* __restrict__ x, const float* __restrict__ gamma,
    float* __restrict__ out) {
  __shared__ alignas(16) char smem[32768];
  unsigned short* As = (unsigned short*)smem;
  unsigned short* Bs = (unsigned short*)(smem + 16384);
  const int lid = blockIdx.x;
  const int swz = (lid & 7) * 256 + (lid >> 3);
  const int ct = swz & 3, nt = (swz >> 2) & 31, b = swz >> 7;
  const int n0 = nt * 128, co0 = ct * 128;
  const unsigned short* Ap = wob + (size_t)co0 * CV_;
  const unsigned short* Bp = oat + (size_t)b * HW_ * CV_ + (size_t)n0 * CV_;
  const int tid = threadIdx.x, lane = tid & 63, wid = tid >> 6;
  const int wc = (wid >> 1) * 64, wn = (wid & 1) * 64;
  f32x4 acc[4][4] = {};
  for (int k0 = 0; k0 < CV_; k0 += 64) {
    __syncthreads();
#pragma unroll
    for (int i = 0; i < 4; ++i) {
      const int r = i * 32 + (tid >> 3);
      const int s = tid & 7;
      const int rw = i * 32 + wid * 8;
      const size_t goff = (size_t)r * CV_ + k0 + (size_t)((s ^ (r & 7)) * 8);
      gload_lds16(&Ap[goff], &As[rw * 64]);
      gload_lds16(&Bp[goff], &Bs[rw * 64]);
    }
    __syncthreads();
#pragma unroll
    for (int kk = 0; kk < 2; ++kk) {
      bf16x8 af[4], bfr[4];
#pragma unroll
      for (int i = 0; i < 4; ++i) {
        const int r = wc + i * 16 + (lane & 15);
        const int slot = (kk * 4 + (lane >> 4)) ^ (r & 7);
        af[i] = *reinterpret_cast<const bf16x8*>(&As[r * 64 + slot * 8]);
      }
#pragma unroll
      for (int j = 0; j < 4; ++j) {
        const int r = wn + j * 16 + (lane & 15);
        const int slot = (kk * 4 + (lane >> 4)) ^ (r & 7);
        bfr[j] = *reinterpret_cast<const bf16x8*>(&Bs[r * 64 + slot * 8]);
      }
#pragma unroll
      for (int i = 0; i < 4; ++i)
#pragma unroll
        for (int j = 0; j < 4; ++j) acc[i][j] = mfma16(af[i], bfr[j], acc[i][j]);
    }
  }
  float* eps = (float*)smem;
  const float g = gamma[0];
  const size_t base = (size_t)b * C_ * HW_;
#pragma unroll
  for (int h = 0; h < 4; ++h) {
    __syncthreads();
    if ((wid >> 1) == (h >> 1)) {
#pragma unroll
      for (int ii = 0; ii < 2; ++ii) {
        const int i = (h & 1) * 2 + ii;
#pragma unroll
        for (int j = 0; j < 4; ++j)
#pragma unroll
          for (int r = 0; r < 4; ++r) {
            const int col2 = ii * 16 + (lane >> 4) * 4 + r;
            const int nl = wn + j * 16 + (lane & 15);
            eps[col2 * 132 + nl] = acc[i][j][r];
          }
      }
    }
    __syncthreads();
#pragma unroll
    for (int t = 0; t < 4; ++t) {
      const int row = t * 8 + (tid >> 5);
      const int col = (tid & 31) * 4;
      const size_t goff = base + (size_t)(co0 + h * 32 + row) * HW_ + n0 + col;
      const f32x4 xv = *reinterpret_cast<const f32x4*>(&x[goff]);
      const f32x4 av = *reinterpret_cast<const f32x4*>(&eps[row * 132 + col]);
      f32x4 ov;
      ov[0] = g * av[0] + xv[0];
      ov[1] = g * av[1] + xv[1];
      ov[2] = g * av[2] + xv[2];
      ov[3] = g * av[3] + xv[3];
      *reinterpret_cast<f32x4*>(&out[goff]) = ov;
    }
  }
}

// ---------------------------------------------------------------- launcher
extern "C" void kernel_launch(void* const* d_in, const int* in_sizes, int n_in,
                              void* d_out, int out_size, void* d_ws, size_t ws_size,
                              hipStream_t stream) {
  (void)in_sizes; (void)n_in; (void)out_size; (void)ws_size;
  const float* x     = (const float*)d_in[0];
  const float* Wq    = (const float*)d_in[1];
  const float* Wk    = (const float*)d_in[2];
  const float* Wv    = (const float*)d_in[3];
  const float* Wo    = (const float*)d_in[4];
  const float* gamma = (const float*)d_in[5];
  float* out = (float*)d_out;
  char* ws = (char*)d_ws;

  unsigned short* wqkv = (unsigned short*)(ws);                 // 384*512*2
  unsigned short* wob  = (unsigned short*)(ws + 393216);        // 512*256*2
  unsigned short* xb   = (unsigned short*)(ws + 655360);        // 64MB
  unsigned short* yt   = (unsigned short*)(ws + 67764224);      // 48MB
  unsigned short* gt   = (unsigned short*)(ws + 118095872);     // 2MB
  unsigned short* vt   = (unsigned short*)(ws + 120193024);     // 8MB
  unsigned short* oat  = xb;   // alias: xb dead after k_gemm_qkv
  float* wt = (float*)yt;      // alias: wT only live during specnorm (yt written later)

  k_transpose<<<dim3(64, 8, 16), 256, 0, stream>>>(x, xb);
  k_wtrans<<<dim3(8, 8, 4), 256, 0, stream>>>(Wq, Wk, Wv, Wo, wt);
  k_specnorm<<<4, 1024, 0, stream>>>(Wq, Wk, Wv, Wo, wt, wqkv, wob);
  k_gemm_qkv<<<1536, 256, 0, stream>>>(xb, wqkv, yt);
  k_pool_g<<<dim3(16, 16), 256, 0, stream>>>(yt, gt);
  k_pool_vt<<<dim3(16, 4, 16), 256, 0, stream>>>(yt, vt);
  k_attn<<<512, 256, 0, stream>>>(yt, gt, vt, oat);
  k_gemm_out<<<2048, 256, 0, stream>>>(oat, wob, x, gamma, out);
}